// Round 1
// baseline (669.483 us; speedup 1.0000x reference)
//
#include <hip/hip_runtime.h>

typedef __attribute__((ext_vector_type(8))) short short8;
typedef __attribute__((ext_vector_type(4))) float f32x4;

constexpr int TT = 2048, CC = 2048, HQ = 16, GG = 4, DD = 128, IC = 8192;

__device__ __forceinline__ ushort f2b(float f) {
  union { float f; unsigned u; } v; v.f = f;
  unsigned r = v.u + 0x7fffu + ((v.u >> 16) & 1u);
  return (ushort)(r >> 16);
}

__device__ __forceinline__ void gload16(const void* g, void* l) {
  __builtin_amdgcn_global_load_lds(
      (const __attribute__((address_space(1))) void*)g,
      (__attribute__((address_space(3))) void*)l, 16, 0, 0);
}

// ---------------- GEMM: C[M,N] = A[M,K](bf16) * B[N,K](bf16)^T ----------------
// EPI 0: Cf = acc ; EPI 1: Cb = hv(acc, alpha, beta) bf16 ; EPI 2: Cf = acc + resid
template<int EPI>
__global__ __launch_bounds__(256)
void gemm_bt(const ushort* __restrict__ A, const ushort* __restrict__ B,
             float* __restrict__ Cf, ushort* __restrict__ Cb,
             const float* __restrict__ alpha, const float* __restrict__ beta,
             const float* __restrict__ resid,
             int M, int N, int K)
{
  __shared__ alignas(16) ushort As[128 * 32];
  __shared__ alignas(16) ushort Bs[128 * 32];
  const int tid = threadIdx.x;
  const int w = tid >> 6, l = tid & 63;
  const int m0 = blockIdx.y * 128, n0 = blockIdx.x * 128;
  const int wr = w >> 1, wc = w & 1;
  const int fl = l & 15, fh = l >> 4;

  f32x4 acc[4][4] = {};

  const int srow = tid >> 2;
  const int scole = (tid & 3) * 8;
  const ushort* Ag = A + (size_t)(m0 + srow) * K + scole;
  const ushort* Bg = B + (size_t)(n0 + srow) * K + scole;
  char* AsB = (char*)As;
  char* BsB = (char*)Bs;

  for (int k0 = 0; k0 < K; k0 += 32) {
    gload16(Ag + k0, AsB + tid * 16);
    gload16(Ag + k0 + (size_t)64 * K, AsB + 4096 + tid * 16);
    gload16(Bg + k0, BsB + tid * 16);
    gload16(Bg + k0 + (size_t)64 * K, BsB + 4096 + tid * 16);
    __syncthreads();
    short8 a[4], b[4];
#pragma unroll
    for (int m = 0; m < 4; ++m)
      a[m] = *(const short8*)(AsB + ((wr * 64 + m * 16 + fl) * 64 + fh * 16));
#pragma unroll
    for (int n = 0; n < 4; ++n)
      b[n] = *(const short8*)(BsB + ((wc * 64 + n * 16 + fl) * 64 + fh * 16));
#pragma unroll
    for (int m = 0; m < 4; ++m)
#pragma unroll
      for (int n = 0; n < 4; ++n)
        acc[m][n] = __builtin_amdgcn_mfma_f32_16x16x32_bf16(a[m], b[n], acc[m][n], 0, 0, 0);
    __syncthreads();
  }

  const int orow0 = m0 + wr * 64 + fh * 4;
  const int ocol0 = n0 + wc * 64 + fl;
#pragma unroll
  for (int m = 0; m < 4; ++m) {
#pragma unroll
    for (int n = 0; n < 4; ++n) {
      const int c = ocol0 + n * 16;
#pragma unroll
      for (int j = 0; j < 4; ++j) {
        const int r = orow0 + m * 16 + j;
        const size_t o = (size_t)r * N + c;
        float v = acc[m][n][j];
        if constexpr (EPI == 0) {
          Cf[o] = v;
        } else if constexpr (EPI == 1) {
          Cb[o] = (v - beta[c] > 0.f) ? f2b(alpha[c]) : (ushort)0;
        } else {
          Cf[o] = v + resid[o];
        }
      }
    }
  }
}

// ---------------- fused causal relu-attention ----------------
// Per block: one head h, 64 q rows. hv epilogue -> h_y bf16 [T][C].
__global__ __launch_bounds__(256)
void attn_kernel(const ushort* __restrict__ qb, const ushort* __restrict__ kb,
                 const ushort* __restrict__ vt, ushort* __restrict__ hy,
                 const float* __restrict__ oalpha, const float* __restrict__ obeta)
{
  __shared__ alignas(16) ushort Qs[64 * 128];  // [q][d] swizzled
  __shared__ alignas(16) ushort Ks[64 * 128];  // [s][d] swizzled
  __shared__ alignas(16) ushort Vs[128 * 64];  // [d][s] swizzled
  __shared__ alignas(16) ushort Ps[64 * 64];   // [q][s] swizzled
  const int qi = blockIdx.x, h = blockIdx.y;
  const int g = h >> 2;
  const int q0 = qi * 64;
  const int tid = threadIdx.x;
  const int w = tid >> 6, l = tid & 63;
  const int fl = l & 15, fh = l >> 4;

  // stage Q once (pre-swizzled global source, linear LDS dest)
#pragma unroll
  for (int i = 0; i < 4; ++i) {
    int row = w * 16 + i * 4 + (l >> 4);
    int c16 = (l & 15) ^ (row & 7);
    gload16(qb + (size_t)h * TT * DD + (size_t)(q0 + row) * DD + c16 * 8,
            (char*)Qs + (w << 12) + (i << 10) + (l << 4));
  }

  f32x4 oacc[8] = {};

  for (int s0 = 0; s0 <= q0; s0 += 64) {
#pragma unroll
    for (int i = 0; i < 4; ++i) {
      int row = w * 16 + i * 4 + (l >> 4);
      int c16 = (l & 15) ^ (row & 7);
      gload16(kb + (size_t)g * TT * DD + (size_t)(s0 + row) * DD + c16 * 8,
              (char*)Ks + (w << 12) + (i << 10) + (l << 4));
    }
#pragma unroll
    for (int i = 0; i < 4; ++i) {
      int d = w * 32 + i * 8 + (l >> 3);
      int c16 = (l & 7) ^ (d & 7);
      gload16(vt + (size_t)g * DD * TT + (size_t)d * TT + s0 + c16 * 8,
              (char*)Vs + (w << 12) + (i << 10) + (l << 4));
    }
    __syncthreads();

    // S = Q K^T  (wave w owns q rows w*16..w*16+15, all 64 s cols)
    f32x4 sacc[4] = {};
    const int qrow = w * 16 + fl;
#pragma unroll
    for (int ks = 0; ks < 4; ++ks) {
      int slotA = (ks * 4 + fh) ^ (qrow & 7);
      short8 a = *(const short8*)((char*)Qs + qrow * 256 + slotA * 16);
#pragma unroll
      for (int n = 0; n < 4; ++n) {
        int krow = n * 16 + fl;
        int slotB = (ks * 4 + fh) ^ (krow & 7);
        short8 b = *(const short8*)((char*)Ks + krow * 256 + slotB * 16);
        sacc[n] = __builtin_amdgcn_mfma_f32_16x16x32_bf16(a, b, sacc[n], 0, 0, 0);
      }
    }

    // P = causal-masked relu(S)/128 -> bf16 in LDS (exact multiples of 1/512)
#pragma unroll
    for (int n = 0; n < 4; ++n) {
      const int scol = s0 + n * 16 + fl;
#pragma unroll
      for (int j = 0; j < 4; ++j) {
        const int pr = w * 16 + fh * 4 + j;
        const int qr = q0 + pr;
        float v = sacc[n][j] * 0.0078125f;
        ushort pv = (scol <= qr && v > 0.f) ? f2b(v) : (ushort)0;
        int slot = ((n * 2) + (fl >> 3)) ^ (pr & 7);
        ((ushort*)((char*)Ps + pr * 128 + slot * 16))[fl & 7] = pv;
      }
    }
    // P rows are wave-local: no barrier needed before PV.

    // O += P V
    const int prow = w * 16 + fl;
#pragma unroll
    for (int ks = 0; ks < 2; ++ks) {
      int slotA = (ks * 4 + fh) ^ (prow & 7);
      short8 pa = *(const short8*)((char*)Ps + prow * 128 + slotA * 16);
#pragma unroll
      for (int n = 0; n < 8; ++n) {
        int vrow = n * 16 + fl;
        int slotB = (ks * 4 + fh) ^ (vrow & 7);
        short8 vb = *(const short8*)((char*)Vs + vrow * 128 + slotB * 16);
        oacc[n] = __builtin_amdgcn_mfma_f32_16x16x32_bf16(pa, vb, oacc[n], 0, 0, 0);
      }
    }
    __syncthreads();
  }

  // epilogue: h_y = hv(y, out_alpha, out_beta)
#pragma unroll
  for (int n = 0; n < 8; ++n) {
    const int c = h * DD + n * 16 + fl;
    const float al = oalpha[c], be = obeta[c];
#pragma unroll
    for (int j = 0; j < 4; ++j) {
      const int tq = q0 + w * 16 + fh * 4 + j;
      float v = oacc[n][j];
      hy[(size_t)tq * CC + c] = (v - be > 0.f) ? f2b(al) : (ushort)0;
    }
  }
}

// ---------------- rope + hv on q/k, transpose+cast v ----------------
__global__ __launch_bounds__(256)
void rope_hv_kernel(const float* __restrict__ qkv, const float* __restrict__ cs,
                    const float* __restrict__ sn,
                    const float* __restrict__ qalpha, const float* __restrict__ qbeta,
                    const float* __restrict__ kalpha, const float* __restrict__ kbeta,
                    ushort* __restrict__ qb, ushort* __restrict__ kb,
                    ushort* __restrict__ vt)
{
  __shared__ ushort Vsh[64][129];
  const int t0 = blockIdx.x * 64, g = blockIdx.y;
  const int tid = threadIdx.x;
#pragma unroll
  for (int hh = 0; hh < 5; ++hh) {
    const float* alpha = (hh < 4) ? qalpha : kalpha;
    const float* beta = (hh < 4) ? qbeta : kbeta;
    const int hoff = (hh < 4) ? hh * 128 : 512;
    for (int it = 0; it < 16; ++it) {
      int idx = it * 256 + tid;
      int tr = idx >> 6, dd = idx & 63;
      size_t base = (size_t)(t0 + tr) * 3072 + g * 768 + hoff;
      float x1 = qkv[base + dd], x2 = qkv[base + 64 + dd];
      float c = cs[(size_t)(t0 + tr) * 64 + dd];
      float s = sn[(size_t)(t0 + tr) * 64 + dd];
      float o1 = x1 * c - x2 * s, o2 = x1 * s + x2 * c;
      ushort b1 = (o1 - beta[dd] > 0.f) ? f2b(alpha[dd]) : (ushort)0;
      ushort b2 = (o2 - beta[64 + dd] > 0.f) ? f2b(alpha[64 + dd]) : (ushort)0;
      if (hh < 4) {
        size_t o = ((size_t)(g * 4 + hh) * TT + t0 + tr) * DD;
        qb[o + dd] = b1;
        qb[o + 64 + dd] = b2;
      } else {
        size_t o = ((size_t)g * TT + t0 + tr) * DD;
        kb[o + dd] = b1;
        kb[o + 64 + dd] = b2;
      }
    }
  }
  // v: cast + transpose -> vt[g][d][t]
  for (int it = 0; it < 32; ++it) {
    int idx = it * 256 + tid;
    int tr = idx >> 7, d = idx & 127;
    Vsh[tr][d] = f2b(qkv[(size_t)(t0 + tr) * 3072 + g * 768 + 640 + d]);
  }
  __syncthreads();
  for (int it = 0; it < 32; ++it) {
    int idx = it * 256 + tid;
    int d = idx >> 6, tl = idx & 63;
    vt[((size_t)g * DD + d) * TT + t0 + tl] = Vsh[tl][d];
  }
}

// ---------------- elementwise ----------------
__global__ void hv_cast_kernel(const float* __restrict__ x, const float* __restrict__ alpha,
                               const float* __restrict__ beta, ushort* __restrict__ out,
                               int n4, int cols) {
  for (int i = blockIdx.x * blockDim.x + threadIdx.x; i < n4; i += gridDim.x * blockDim.x) {
    float4 v = ((const float4*)x)[i];
    int c = (i * 4) & (cols - 1);
    ushort4 r;
    r.x = (v.x - beta[c] > 0.f) ? f2b(alpha[c]) : (ushort)0;
    r.y = (v.y - beta[c + 1] > 0.f) ? f2b(alpha[c + 1]) : (ushort)0;
    r.z = (v.z - beta[c + 2] > 0.f) ? f2b(alpha[c + 2]) : (ushort)0;
    r.w = (v.w - beta[c + 3] > 0.f) ? f2b(alpha[c + 3]) : (ushort)0;
    ((ushort4*)out)[i] = r;
  }
}

__global__ void cast_kernel(const float* __restrict__ x, ushort* __restrict__ out, int n4) {
  for (int i = blockIdx.x * blockDim.x + threadIdx.x; i < n4; i += gridDim.x * blockDim.x) {
    float4 v = ((const float4*)x)[i];
    ushort4 r;
    r.x = f2b(v.x); r.y = f2b(v.y); r.z = f2b(v.z); r.w = f2b(v.w);
    ((ushort4*)out)[i] = r;
  }
}

__global__ void norm_cast_kernel(const float* __restrict__ W, const float* __restrict__ mu,
                                 const float* __restrict__ inv, ushort* __restrict__ out,
                                 int n4, int cols) {
  for (int i = blockIdx.x * blockDim.x + threadIdx.x; i < n4; i += gridDim.x * blockDim.x) {
    float4 v = ((const float4*)W)[i];
    int c = (i * 4) & (cols - 1);
    ushort4 r;
    r.x = f2b((v.x - mu[c]) * inv[c]);
    r.y = f2b((v.y - mu[c + 1]) * inv[c + 1]);
    r.z = f2b((v.z - mu[c + 2]) * inv[c + 2]);
    r.w = f2b((v.w - mu[c + 3]) * inv[c + 3]);
    ((ushort4*)out)[i] = r;
  }
}

// ---------------- column stats for _normed_linear ----------------
__global__ void stats1_kernel(const float* __restrict__ W, float* __restrict__ ps,
                              float* __restrict__ ps2, int cols) {
  int j = blockIdx.x * 256 + threadIdx.x;
  int chunk = blockIdx.y;
  const float* p = W + (size_t)chunk * 256 * cols + j;
  float s = 0.f, s2 = 0.f;
  for (int i = 0; i < 256; ++i) { float v = p[(size_t)i * cols]; s += v; s2 += v * v; }
  ps[chunk * cols + j] = s;
  ps2[chunk * cols + j] = s2;
}

__global__ void stats2_kernel(const float* __restrict__ ps, const float* __restrict__ ps2,
                              float* __restrict__ mu, float* __restrict__ inv,
                              const float* __restrict__ scale, int cols) {
  int j = blockIdx.x * 256 + threadIdx.x;
  float s = 0.f, s2 = 0.f;
  for (int c = 0; c < 8; ++c) { s += ps[c * cols + j]; s2 += ps2[c * cols + j]; }
  float m = s * (1.f / 2048.f);
  float var = s2 - s * m;
  float nn = sqrtf(fmaxf(var, 0.f));
  nn = fmaxf(nn, 1e-12f);
  mu[j] = m;
  inv[j] = scale[0] / nn;
}

extern "C" void kernel_launch(void* const* d_in, const int* in_sizes, int n_in,
                              void* d_out, int out_size, void* d_ws, size_t ws_size,
                              hipStream_t stream) {
  const float* x          = (const float*)d_in[0];
  const float* cosT       = (const float*)d_in[1];
  const float* sinT       = (const float*)d_in[2];
  const float* attn_w     = (const float*)d_in[3];
  const float* proj_w     = (const float*)d_in[4];
  const float* proj_scale = (const float*)d_in[5];
  const float* fc_w       = (const float*)d_in[6];
  const float* mlp_proj_w = (const float*)d_in[7];
  const float* mlp_scale  = (const float*)d_in[8];
  const float* in_alpha   = (const float*)d_in[9];
  const float* in_beta    = (const float*)d_in[10];
  const float* q_alpha    = (const float*)d_in[11];
  const float* q_beta     = (const float*)d_in[12];
  const float* k_alpha    = (const float*)d_in[13];
  const float* k_beta     = (const float*)d_in[14];
  const float* out_alpha  = (const float*)d_in[15];
  const float* out_beta   = (const float*)d_in[16];
  const float* act1_alpha = (const float*)d_in[17];
  const float* act1_beta  = (const float*)d_in[18];
  const float* act2_alpha = (const float*)d_in[19];
  const float* act2_beta  = (const float*)d_in[20];

  char* cur = (char*)d_ws;
  auto alloc = [&](size_t b) { void* p = cur; cur += (b + 255) & ~(size_t)255; return p; };

  ushort* attn_wb = (ushort*)alloc((size_t)3072 * 2048 * 2);
  ushort* fc_wb   = (ushort*)alloc((size_t)8192 * 2048 * 2);
  ushort* projn   = (ushort*)alloc((size_t)2048 * 2048 * 2);
  ushort* mlpn    = (ushort*)alloc((size_t)2048 * 8192 * 2);
  ushort* h_in    = (ushort*)alloc((size_t)2048 * 2048 * 2);
  float*  qkv     = (float*)alloc((size_t)2048 * 3072 * 4);
  ushort* qbuf    = (ushort*)alloc((size_t)HQ * TT * DD * 2);
  ushort* kbuf    = (ushort*)alloc((size_t)GG * TT * DD * 2);
  ushort* vtbuf   = (ushort*)alloc((size_t)GG * DD * TT * 2);
  ushort* h_y     = (ushort*)alloc((size_t)2048 * 2048 * 2);
  float*  x2      = (float*)alloc((size_t)2048 * 2048 * 4);
  ushort* h2      = (ushort*)alloc((size_t)2048 * 2048 * 2);
  ushort* h3      = (ushort*)alloc((size_t)2048 * 8192 * 2);
  float* pp_s  = (float*)alloc(8 * 2048 * 4);
  float* pp_s2 = (float*)alloc(8 * 2048 * 4);
  float* mp_s  = (float*)alloc(8 * 8192 * 4);
  float* mp_s2 = (float*)alloc(8 * 8192 * 4);
  float* p_mu  = (float*)alloc(2048 * 4);
  float* p_inv = (float*)alloc(2048 * 4);
  float* m_mu  = (float*)alloc(8192 * 4);
  float* m_inv = (float*)alloc(8192 * 4);

  // weight prep
  stats1_kernel<<<dim3(8, 8), 256, 0, stream>>>(proj_w, pp_s, pp_s2, 2048);
  stats1_kernel<<<dim3(32, 8), 256, 0, stream>>>(mlp_proj_w, mp_s, mp_s2, 8192);
  stats2_kernel<<<8, 256, 0, stream>>>(pp_s, pp_s2, p_mu, p_inv, proj_scale, 2048);
  stats2_kernel<<<32, 256, 0, stream>>>(mp_s, mp_s2, m_mu, m_inv, mlp_scale, 8192);
  norm_cast_kernel<<<2048, 256, 0, stream>>>(proj_w, p_mu, p_inv, projn, 2048 * 2048 / 4, 2048);
  norm_cast_kernel<<<2048, 256, 0, stream>>>(mlp_proj_w, m_mu, m_inv, mlpn, 2048 * 8192 / 4, 8192);
  cast_kernel<<<2048, 256, 0, stream>>>(attn_w, attn_wb, 3072 * 2048 / 4);
  cast_kernel<<<2048, 256, 0, stream>>>(fc_w, fc_wb, 8192 * 2048 / 4);

  // h = hv(x)
  hv_cast_kernel<<<2048, 256, 0, stream>>>(x, in_alpha, in_beta, h_in, 2048 * 2048 / 4, 2048);

  // qkv = h @ attn_w^T
  gemm_bt<0><<<dim3(3072 / 128, 2048 / 128), 256, 0, stream>>>(
      h_in, attn_wb, qkv, nullptr, nullptr, nullptr, nullptr, 2048, 3072, 2048);

  // rope + hv -> q,k ; transpose v
  rope_hv_kernel<<<dim3(TT / 64, GG), 256, 0, stream>>>(
      qkv, cosT, sinT, q_alpha, q_beta, k_alpha, k_beta, qbuf, kbuf, vtbuf);

  // fused causal relu attention, hv epilogue -> h_y
  attn_kernel<<<dim3(TT / 64, HQ), 256, 0, stream>>>(qbuf, kbuf, vtbuf, h_y, out_alpha, out_beta);

  // x2 = x + h_y @ projn^T
  gemm_bt<2><<<dim3(2048 / 128, 2048 / 128), 256, 0, stream>>>(
      h_y, projn, x2, nullptr, nullptr, nullptr, x, 2048, 2048, 2048);

  // h2 = hv(x2)
  hv_cast_kernel<<<2048, 256, 0, stream>>>(x2, act1_alpha, act1_beta, h2, 2048 * 2048 / 4, 2048);

  // h3 = hv(h2 @ fc_w^T)
  gemm_bt<1><<<dim3(8192 / 128, 2048 / 128), 256, 0, stream>>>(
      h2, fc_wb, nullptr, h3, act2_alpha, act2_beta, nullptr, 2048, 8192, 2048);

  // out = x2 + h3 @ mlpn^T
  gemm_bt<2><<<dim3(2048 / 128, 2048 / 128), 256, 0, stream>>>(
      h3, mlpn, (float*)d_out, nullptr, nullptr, nullptr, x2, 2048, 2048, 8192);
}

// Round 2
// 536.805 us; speedup vs baseline: 1.2472x; 1.2472x over previous
//
#include <hip/hip_runtime.h>

typedef __attribute__((ext_vector_type(8))) short short8;
typedef __attribute__((ext_vector_type(4))) float f32x4;

constexpr int TT = 2048, CC = 2048, HQ = 16, GG = 4, DD = 128, IC = 8192;

__device__ __forceinline__ ushort f2b(float f) {
  union { float f; unsigned u; } v; v.f = f;
  unsigned r = v.u + 0x7fffu + ((v.u >> 16) & 1u);
  return (ushort)(r >> 16);
}

__device__ __forceinline__ void gload16(const void* g, void* l) {
  __builtin_amdgcn_global_load_lds(
      (const __attribute__((address_space(1))) void*)g,
      (__attribute__((address_space(3))) void*)l, 16, 0, 0);
}

// ---------------- GEMM: C[M,N] = A[M,K](bf16) * B[N,K](bf16)^T ----------------
// EPI 0: Cf = acc ; EPI 1: Cb = hv(acc) ; EPI 2: Cf = acc + resid ; EPI 3: partial (split-K)
// 2-phase double-buffered LDS: prefetch tile t+1 while computing tile t.
template<int EPI>
__global__ __launch_bounds__(256)
void gemm_bt(const ushort* __restrict__ A, const ushort* __restrict__ B,
             float* __restrict__ Cf, ushort* __restrict__ Cb,
             const float* __restrict__ alpha, const float* __restrict__ beta,
             const float* __restrict__ resid,
             int M, int N, int K, int kc)
{
  __shared__ alignas(16) ushort As[2][4096];
  __shared__ alignas(16) ushort Bs[2][4096];
  const int tid = threadIdx.x;
  const int w = tid >> 6, l = tid & 63;
  const int m0 = blockIdx.y * 128, n0 = blockIdx.x * 128;
  const int wr = w >> 1, wc = w & 1;
  const int fl = l & 15, fh = l >> 4;

  const int kBeg = blockIdx.z * kc;
  const int kEnd = (kBeg + kc < K) ? (kBeg + kc) : K;
  const int nt = (kEnd - kBeg) >> 5;

  f32x4 acc[4][4] = {};

  const int srow = tid >> 2;
  const int scole = (tid & 3) * 8;
  const ushort* Ag = A + (size_t)(m0 + srow) * K + scole + kBeg;
  const ushort* Bg = B + (size_t)(n0 + srow) * K + scole + kBeg;

  auto stage = [&](int buf, int t) {
    const int k0 = t << 5;
    gload16(Ag + k0, (char*)As[buf] + tid * 16);
    gload16(Ag + k0 + (size_t)64 * K, (char*)As[buf] + 4096 + tid * 16);
    gload16(Bg + k0, (char*)Bs[buf] + tid * 16);
    gload16(Bg + k0 + (size_t)64 * K, (char*)Bs[buf] + 4096 + tid * 16);
  };

  stage(0, 0);
  __syncthreads();
  int cur = 0;
  for (int t = 0; t < nt; ++t) {
    if (t + 1 < nt) stage(cur ^ 1, t + 1);
    short8 a[4], b[4];
#pragma unroll
    for (int m = 0; m < 4; ++m)
      a[m] = *(const short8*)((char*)As[cur] + ((wr * 64 + m * 16 + fl) * 64 + fh * 16));
#pragma unroll
    for (int n = 0; n < 4; ++n)
      b[n] = *(const short8*)((char*)Bs[cur] + ((wc * 64 + n * 16 + fl) * 64 + fh * 16));
#pragma unroll
    for (int m = 0; m < 4; ++m)
#pragma unroll
      for (int n = 0; n < 4; ++n)
        acc[m][n] = __builtin_amdgcn_mfma_f32_16x16x32_bf16(a[m], b[n], acc[m][n], 0, 0, 0);
    __syncthreads();   // vmcnt(0) drain: prefetched tile ready; cur buffer free
    cur ^= 1;
  }

  const int orow0 = m0 + wr * 64 + fh * 4;
  const int ocol0 = n0 + wc * 64 + fl;
  float* Cpart = (EPI == 3) ? (Cf + (size_t)blockIdx.z * M * N) : Cf;
#pragma unroll
  for (int m = 0; m < 4; ++m) {
#pragma unroll
    for (int n = 0; n < 4; ++n) {
      const int c = ocol0 + n * 16;
#pragma unroll
      for (int j = 0; j < 4; ++j) {
        const int r = orow0 + m * 16 + j;
        const size_t o = (size_t)r * N + c;
        float v = acc[m][n][j];
        if constexpr (EPI == 0) {
          Cf[o] = v;
        } else if constexpr (EPI == 1) {
          Cb[o] = (v - beta[c] > 0.f) ? f2b(alpha[c]) : (ushort)0;
        } else if constexpr (EPI == 2) {
          Cf[o] = v + resid[o];
        } else {
          Cpart[o] = v;
        }
      }
    }
  }
}

// ---------------- split-K reduce ----------------
// MODE 0: outf = sum(parts) ; MODE 1: outf = resid+sum, outb = hv(outf) ; MODE 2: outf = resid+sum
template<int NS, int MODE>
__global__ void reduce_kernel(const float* __restrict__ parts, int planeN4,
                              const float* __restrict__ resid,
                              float* __restrict__ outf, ushort* __restrict__ outb,
                              const float* __restrict__ alpha, const float* __restrict__ beta,
                              int n4, int cols)
{
  for (int i = blockIdx.x * blockDim.x + threadIdx.x; i < n4; i += gridDim.x * blockDim.x) {
    float4 s = ((const float4*)parts)[i];
#pragma unroll
    for (int z = 1; z < NS; ++z) {
      float4 p = ((const float4*)parts)[(size_t)z * planeN4 + i];
      s.x += p.x; s.y += p.y; s.z += p.z; s.w += p.w;
    }
    if constexpr (MODE >= 1) {
      float4 rr = ((const float4*)resid)[i];
      s.x += rr.x; s.y += rr.y; s.z += rr.z; s.w += rr.w;
    }
    ((float4*)outf)[i] = s;
    if constexpr (MODE == 1) {
      int c = (i * 4) & (cols - 1);
      ushort4 r;
      r.x = (s.x - beta[c] > 0.f) ? f2b(alpha[c]) : (ushort)0;
      r.y = (s.y - beta[c + 1] > 0.f) ? f2b(alpha[c + 1]) : (ushort)0;
      r.z = (s.z - beta[c + 2] > 0.f) ? f2b(alpha[c + 2]) : (ushort)0;
      r.w = (s.w - beta[c + 3] > 0.f) ? f2b(alpha[c + 3]) : (ushort)0;
      ((ushort4*)outb)[i] = r;
    }
  }
}

// ---------------- fused causal relu-attention ----------------
__global__ __launch_bounds__(256)
void attn_kernel(const ushort* __restrict__ qb, const ushort* __restrict__ kb,
                 const ushort* __restrict__ vt, ushort* __restrict__ hy,
                 const float* __restrict__ oalpha, const float* __restrict__ obeta)
{
  __shared__ alignas(16) ushort Qs[64 * 128];
  __shared__ alignas(16) ushort Ks[64 * 128];
  __shared__ alignas(16) ushort Vs[128 * 64];
  __shared__ alignas(16) ushort Ps[64 * 64];
  const int qi = blockIdx.x, h = blockIdx.y;
  const int g = h >> 2;
  const int q0 = qi * 64;
  const int tid = threadIdx.x;
  const int w = tid >> 6, l = tid & 63;
  const int fl = l & 15, fh = l >> 4;

#pragma unroll
  for (int i = 0; i < 4; ++i) {
    int row = w * 16 + i * 4 + (l >> 4);
    int c16 = (l & 15) ^ (row & 7);
    gload16(qb + (size_t)h * TT * DD + (size_t)(q0 + row) * DD + c16 * 8,
            (char*)Qs + (w << 12) + (i << 10) + (l << 4));
  }

  f32x4 oacc[8] = {};

  for (int s0 = 0; s0 <= q0; s0 += 64) {
#pragma unroll
    for (int i = 0; i < 4; ++i) {
      int row = w * 16 + i * 4 + (l >> 4);
      int c16 = (l & 15) ^ (row & 7);
      gload16(kb + (size_t)g * TT * DD + (size_t)(s0 + row) * DD + c16 * 8,
              (char*)Ks + (w << 12) + (i << 10) + (l << 4));
    }
#pragma unroll
    for (int i = 0; i < 4; ++i) {
      int d = w * 32 + i * 8 + (l >> 3);
      int c16 = (l & 7) ^ (d & 7);
      gload16(vt + (size_t)g * DD * TT + (size_t)d * TT + s0 + c16 * 8,
              (char*)Vs + (w << 12) + (i << 10) + (l << 4));
    }
    __syncthreads();

    f32x4 sacc[4] = {};
    const int qrow = w * 16 + fl;
#pragma unroll
    for (int ks = 0; ks < 4; ++ks) {
      int slotA = (ks * 4 + fh) ^ (qrow & 7);
      short8 a = *(const short8*)((char*)Qs + qrow * 256 + slotA * 16);
#pragma unroll
      for (int n = 0; n < 4; ++n) {
        int krow = n * 16 + fl;
        int slotB = (ks * 4 + fh) ^ (krow & 7);
        short8 b = *(const short8*)((char*)Ks + krow * 256 + slotB * 16);
        sacc[n] = __builtin_amdgcn_mfma_f32_16x16x32_bf16(a, b, sacc[n], 0, 0, 0);
      }
    }

#pragma unroll
    for (int n = 0; n < 4; ++n) {
      const int scol = s0 + n * 16 + fl;
#pragma unroll
      for (int j = 0; j < 4; ++j) {
        const int pr = w * 16 + fh * 4 + j;
        const int qr = q0 + pr;
        float v = sacc[n][j] * 0.0078125f;
        ushort pv = (scol <= qr && v > 0.f) ? f2b(v) : (ushort)0;
        int slot = ((n * 2) + (fl >> 3)) ^ (pr & 7);
        ((ushort*)((char*)Ps + pr * 128 + slot * 16))[fl & 7] = pv;
      }
    }

    const int prow = w * 16 + fl;
#pragma unroll
    for (int ks = 0; ks < 2; ++ks) {
      int slotA = (ks * 4 + fh) ^ (prow & 7);
      short8 pa = *(const short8*)((char*)Ps + prow * 128 + slotA * 16);
#pragma unroll
      for (int n = 0; n < 8; ++n) {
        int vrow = n * 16 + fl;
        int slotB = (ks * 4 + fh) ^ (vrow & 7);
        short8 vb = *(const short8*)((char*)Vs + vrow * 128 + slotB * 16);
        oacc[n] = __builtin_amdgcn_mfma_f32_16x16x32_bf16(pa, vb, oacc[n], 0, 0, 0);
      }
    }
    __syncthreads();
  }

#pragma unroll
  for (int n = 0; n < 8; ++n) {
    const int c = h * DD + n * 16 + fl;
    const float al = oalpha[c], be = obeta[c];
#pragma unroll
    for (int j = 0; j < 4; ++j) {
      const int tq = q0 + w * 16 + fh * 4 + j;
      float v = oacc[n][j];
      hy[(size_t)tq * CC + c] = (v - be > 0.f) ? f2b(al) : (ushort)0;
    }
  }
}

// ---------------- rope + hv on q/k, transpose+cast v ----------------
__global__ __launch_bounds__(256)
void rope_hv_kernel(const float* __restrict__ qkv, const float* __restrict__ cs,
                    const float* __restrict__ sn,
                    const float* __restrict__ qalpha, const float* __restrict__ qbeta,
                    const float* __restrict__ kalpha, const float* __restrict__ kbeta,
                    ushort* __restrict__ qb, ushort* __restrict__ kb,
                    ushort* __restrict__ vt)
{
  __shared__ ushort Vsh[64][129];
  const int t0 = blockIdx.x * 64, g = blockIdx.y;
  const int tid = threadIdx.x;
#pragma unroll
  for (int hh = 0; hh < 5; ++hh) {
    const float* alpha = (hh < 4) ? qalpha : kalpha;
    const float* beta = (hh < 4) ? qbeta : kbeta;
    const int hoff = (hh < 4) ? hh * 128 : 512;
    for (int it = 0; it < 16; ++it) {
      int idx = it * 256 + tid;
      int tr = idx >> 6, dd = idx & 63;
      size_t base = (size_t)(t0 + tr) * 3072 + g * 768 + hoff;
      float x1 = qkv[base + dd], x2 = qkv[base + 64 + dd];
      float c = cs[(size_t)(t0 + tr) * 64 + dd];
      float s = sn[(size_t)(t0 + tr) * 64 + dd];
      float o1 = x1 * c - x2 * s, o2 = x1 * s + x2 * c;
      ushort b1 = (o1 - beta[dd] > 0.f) ? f2b(alpha[dd]) : (ushort)0;
      ushort b2 = (o2 - beta[64 + dd] > 0.f) ? f2b(alpha[64 + dd]) : (ushort)0;
      if (hh < 4) {
        size_t o = ((size_t)(g * 4 + hh) * TT + t0 + tr) * DD;
        qb[o + dd] = b1;
        qb[o + 64 + dd] = b2;
      } else {
        size_t o = ((size_t)g * TT + t0 + tr) * DD;
        kb[o + dd] = b1;
        kb[o + 64 + dd] = b2;
      }
    }
  }
  for (int it = 0; it < 32; ++it) {
    int idx = it * 256 + tid;
    int tr = idx >> 7, d = idx & 127;
    Vsh[tr][d] = f2b(qkv[(size_t)(t0 + tr) * 3072 + g * 768 + 640 + d]);
  }
  __syncthreads();
  for (int it = 0; it < 32; ++it) {
    int idx = it * 256 + tid;
    int d = idx >> 6, tl = idx & 63;
    vt[((size_t)g * DD + d) * TT + t0 + tl] = Vsh[tl][d];
  }
}

// ---------------- elementwise ----------------
__global__ void hv_cast_kernel(const float* __restrict__ x, const float* __restrict__ alpha,
                               const float* __restrict__ beta, ushort* __restrict__ out,
                               int n4, int cols) {
  for (int i = blockIdx.x * blockDim.x + threadIdx.x; i < n4; i += gridDim.x * blockDim.x) {
    float4 v = ((const float4*)x)[i];
    int c = (i * 4) & (cols - 1);
    ushort4 r;
    r.x = (v.x - beta[c] > 0.f) ? f2b(alpha[c]) : (ushort)0;
    r.y = (v.y - beta[c + 1] > 0.f) ? f2b(alpha[c + 1]) : (ushort)0;
    r.z = (v.z - beta[c + 2] > 0.f) ? f2b(alpha[c + 2]) : (ushort)0;
    r.w = (v.w - beta[c + 3] > 0.f) ? f2b(alpha[c + 3]) : (ushort)0;
    ((ushort4*)out)[i] = r;
  }
}

__global__ void cast_kernel(const float* __restrict__ x, ushort* __restrict__ out, int n4) {
  for (int i = blockIdx.x * blockDim.x + threadIdx.x; i < n4; i += gridDim.x * blockDim.x) {
    float4 v = ((const float4*)x)[i];
    ushort4 r;
    r.x = f2b(v.x); r.y = f2b(v.y); r.z = f2b(v.z); r.w = f2b(v.w);
    ((ushort4*)out)[i] = r;
  }
}

__global__ void norm_cast_kernel(const float* __restrict__ W, const float* __restrict__ mu,
                                 const float* __restrict__ inv, ushort* __restrict__ out,
                                 int n4, int cols) {
  for (int i = blockIdx.x * blockDim.x + threadIdx.x; i < n4; i += gridDim.x * blockDim.x) {
    float4 v = ((const float4*)W)[i];
    int c = (i * 4) & (cols - 1);
    ushort4 r;
    r.x = f2b((v.x - mu[c]) * inv[c]);
    r.y = f2b((v.y - mu[c + 1]) * inv[c + 1]);
    r.z = f2b((v.z - mu[c + 2]) * inv[c + 2]);
    r.w = f2b((v.w - mu[c + 3]) * inv[c + 3]);
    ((ushort4*)out)[i] = r;
  }
}

// ---------------- column stats ----------------
__global__ void stats1_kernel(const float* __restrict__ W, float* __restrict__ ps,
                              float* __restrict__ ps2, int cols) {
  int j = blockIdx.x * 256 + threadIdx.x;
  int chunk = blockIdx.y;
  const float* p = W + (size_t)chunk * 256 * cols + j;
  float s = 0.f, s2 = 0.f;
  for (int i = 0; i < 256; ++i) { float v = p[(size_t)i * cols]; s += v; s2 += v * v; }
  ps[chunk * cols + j] = s;
  ps2[chunk * cols + j] = s2;
}

__global__ void stats2_kernel(const float* __restrict__ ps, const float* __restrict__ ps2,
                              float* __restrict__ mu, float* __restrict__ inv,
                              const float* __restrict__ scale, int cols) {
  int j = blockIdx.x * 256 + threadIdx.x;
  float s = 0.f, s2 = 0.f;
  for (int c = 0; c < 8; ++c) { s += ps[c * cols + j]; s2 += ps2[c * cols + j]; }
  float m = s * (1.f / 2048.f);
  float var = s2 - s * m;
  float nn = sqrtf(fmaxf(var, 0.f));
  nn = fmaxf(nn, 1e-12f);
  mu[j] = m;
  inv[j] = scale[0] / nn;
}

extern "C" void kernel_launch(void* const* d_in, const int* in_sizes, int n_in,
                              void* d_out, int out_size, void* d_ws, size_t ws_size,
                              hipStream_t stream) {
  const float* x          = (const float*)d_in[0];
  const float* cosT       = (const float*)d_in[1];
  const float* sinT       = (const float*)d_in[2];
  const float* attn_w     = (const float*)d_in[3];
  const float* proj_w     = (const float*)d_in[4];
  const float* proj_scale = (const float*)d_in[5];
  const float* fc_w       = (const float*)d_in[6];
  const float* mlp_proj_w = (const float*)d_in[7];
  const float* mlp_scale  = (const float*)d_in[8];
  const float* in_alpha   = (const float*)d_in[9];
  const float* in_beta    = (const float*)d_in[10];
  const float* q_alpha    = (const float*)d_in[11];
  const float* q_beta     = (const float*)d_in[12];
  const float* k_alpha    = (const float*)d_in[13];
  const float* k_beta     = (const float*)d_in[14];
  const float* out_alpha  = (const float*)d_in[15];
  const float* out_beta   = (const float*)d_in[16];
  const float* act1_alpha = (const float*)d_in[17];
  const float* act1_beta  = (const float*)d_in[18];
  const float* act2_alpha = (const float*)d_in[19];
  const float* act2_beta  = (const float*)d_in[20];

  char* cur = (char*)d_ws;
  auto alloc = [&](size_t b) { void* p = cur; cur += (b + 255) & ~(size_t)255; return p; };

  ushort* attn_wb = (ushort*)alloc((size_t)3072 * 2048 * 2);   // dead after qkv GEMM
  ushort* fc_wb   = (ushort*)alloc((size_t)8192 * 2048 * 2);   // dead after fc GEMM
  ushort* projn   = (ushort*)alloc((size_t)2048 * 2048 * 2);   // dead after proj GEMM
  ushort* mlpn    = (ushort*)alloc((size_t)2048 * 8192 * 2);
  ushort* h_in    = (ushort*)alloc((size_t)2048 * 2048 * 2);   // dead after qkv GEMM
  float*  qkv     = (float*)alloc((size_t)2048 * 3072 * 4);    // dead after rope
  ushort* qbuf    = (ushort*)alloc((size_t)HQ * TT * DD * 2);
  ushort* kbuf    = (ushort*)alloc((size_t)GG * TT * DD * 2);
  ushort* vtbuf   = (ushort*)alloc((size_t)GG * DD * TT * 2);
  ushort* h_y     = (ushort*)alloc((size_t)2048 * 2048 * 2);
  float*  x2      = (float*)alloc((size_t)2048 * 2048 * 4);
  ushort* h2      = (ushort*)alloc((size_t)2048 * 2048 * 2);
  ushort* h3      = (ushort*)alloc((size_t)2048 * 8192 * 2);
  float* pp_s  = (float*)alloc(8 * 2048 * 4);
  float* pp_s2 = (float*)alloc(8 * 2048 * 4);
  float* mp_s  = (float*)alloc(8 * 8192 * 4);
  float* mp_s2 = (float*)alloc(8 * 8192 * 4);
  float* p_mu  = (float*)alloc(2048 * 4);
  float* p_inv = (float*)alloc(2048 * 4);
  float* m_mu  = (float*)alloc(8192 * 4);
  float* m_inv = (float*)alloc(8192 * 4);

  // split-K part buffers alias dead regions (all sizes are 256-aligned):
  float* qkv_parts  = (float*)x2;      // 2 x 25.2MB = 50.3MB over x2+h2+h3 (58.7MB), dead then
  float* proj_parts = (float*)h_in;    // 2 x 16.8MB = 33.6MB over h_in+qkv (33.6MB), dead then
  float* mlp_parts  = (float*)attn_wb; // 3 x 16.8MB = 50.3MB over attn_wb+fc_wb+projn (54.5MB), dead then

  // weight prep
  stats1_kernel<<<dim3(8, 8), 256, 0, stream>>>(proj_w, pp_s, pp_s2, 2048);
  stats1_kernel<<<dim3(32, 8), 256, 0, stream>>>(mlp_proj_w, mp_s, mp_s2, 8192);
  stats2_kernel<<<8, 256, 0, stream>>>(pp_s, pp_s2, p_mu, p_inv, proj_scale, 2048);
  stats2_kernel<<<32, 256, 0, stream>>>(mp_s, mp_s2, m_mu, m_inv, mlp_scale, 8192);
  norm_cast_kernel<<<2048, 256, 0, stream>>>(proj_w, p_mu, p_inv, projn, 2048 * 2048 / 4, 2048);
  norm_cast_kernel<<<2048, 256, 0, stream>>>(mlp_proj_w, m_mu, m_inv, mlpn, 2048 * 8192 / 4, 8192);
  cast_kernel<<<2048, 256, 0, stream>>>(attn_w, attn_wb, 3072 * 2048 / 4);
  cast_kernel<<<2048, 256, 0, stream>>>(fc_w, fc_wb, 8192 * 2048 / 4);

  // h = hv(x)
  hv_cast_kernel<<<2048, 256, 0, stream>>>(x, in_alpha, in_beta, h_in, 2048 * 2048 / 4, 2048);

  // qkv = h @ attn_w^T   (split-K x2)
  gemm_bt<3><<<dim3(3072 / 128, 2048 / 128, 2), 256, 0, stream>>>(
      h_in, attn_wb, qkv_parts, nullptr, nullptr, nullptr, nullptr, 2048, 3072, 2048, 1024);
  reduce_kernel<2, 0><<<2048, 256, 0, stream>>>(
      qkv_parts, 2048 * 3072 / 4, nullptr, qkv, nullptr, nullptr, nullptr, 2048 * 3072 / 4, 1);

  // rope + hv -> q,k ; transpose v
  rope_hv_kernel<<<dim3(TT / 64, GG), 256, 0, stream>>>(
      qkv, cosT, sinT, q_alpha, q_beta, k_alpha, k_beta, qbuf, kbuf, vtbuf);

  // fused causal relu attention, hv epilogue -> h_y
  attn_kernel<<<dim3(TT / 64, HQ), 256, 0, stream>>>(qbuf, kbuf, vtbuf, h_y, out_alpha, out_beta);

  // x2 = x + h_y @ projn^T (split-K x2), fused: h2 = hv(x2)
  gemm_bt<3><<<dim3(2048 / 128, 2048 / 128, 2), 256, 0, stream>>>(
      h_y, projn, proj_parts, nullptr, nullptr, nullptr, nullptr, 2048, 2048, 2048, 1024);
  reduce_kernel<2, 1><<<2048, 256, 0, stream>>>(
      proj_parts, 2048 * 2048 / 4, x, x2, h2, act1_alpha, act1_beta, 2048 * 2048 / 4, 2048);

  // h3 = hv(h2 @ fc_w^T)   (1024 blocks already; no split)
  gemm_bt<1><<<dim3(8192 / 128, 2048 / 128, 1), 256, 0, stream>>>(
      h2, fc_wb, nullptr, h3, act2_alpha, act2_beta, nullptr, 2048, 8192, 2048, 2048);

  // out = x2 + h3 @ mlpn^T (split-K x3, kc=2752 so slices are 86/86/84 K-steps)
  gemm_bt<3><<<dim3(2048 / 128, 2048 / 128, 3), 256, 0, stream>>>(
      h3, mlpn, mlp_parts, nullptr, nullptr, nullptr, nullptr, 2048, 2048, 8192, 2752);
  reduce_kernel<3, 2><<<2048, 256, 0, stream>>>(
      mlp_parts, 2048 * 2048 / 4, x2, (float*)d_out, nullptr, nullptr, nullptr, 2048 * 2048 / 4, 1);
}

// Round 3
// 475.176 us; speedup vs baseline: 1.4089x; 1.1297x over previous
//
#include <hip/hip_runtime.h>

typedef __attribute__((ext_vector_type(8))) short short8;
typedef __attribute__((ext_vector_type(4))) float f32x4;

constexpr int TT = 2048, CC = 2048, HQ = 16, GG = 4, DD = 128, IC = 8192;

__device__ __forceinline__ ushort f2b(float f) {
  union { float f; unsigned u; } v; v.f = f;
  unsigned r = v.u + 0x7fffu + ((v.u >> 16) & 1u);
  return (ushort)(r >> 16);
}

__device__ __forceinline__ void gload16(const void* g, void* l) {
  __builtin_amdgcn_global_load_lds(
      (const __attribute__((address_space(1))) void*)g,
      (__attribute__((address_space(3))) void*)l, 16, 0, 0);
}

#define BAR()    __builtin_amdgcn_s_barrier()
#define WAITLG() asm volatile("s_waitcnt lgkmcnt(0)" ::: "memory")
#define SCHED0() __builtin_amdgcn_sched_barrier(0)
#define PRIO1()  __builtin_amdgcn_s_setprio(1)
#define PRIO0()  __builtin_amdgcn_s_setprio(0)

// ============ 256x256 8-phase GEMM: C[M,N] = A[M,K](bf16) @ B[N,K](bf16)^T ============
// EPI 1: Cb = hv(acc, alpha, beta) bf16 ; EPI 3: f32 partial plane per blockIdx.z
// 8 waves (2M x 4N), per-wave 128x64 output, BK=64, LDS 128KB double-buffered.
// LDS tiles [256 rows][8 slots of 16B], content of (row, slot) = k-slot (slot ^ (row&7))
// (swizzle applied on the GLOBAL source; LDS dest linear — both-sides rule).
// Stage slots per K-tile s: ph1: Ah0(s+1), ph2: Ah1(s+1), ph3: Bh0(s+2), ph4: Bh1(s+2).
// Boundary wait vmcnt(4): 2 half-tiles (4 loads) of s+2 may remain in flight.
template<int EPI>
__global__ __launch_bounds__(512, 2)
void gemm8p(const ushort* __restrict__ A, const ushort* __restrict__ B,
            float* __restrict__ Cf, ushort* __restrict__ Cb,
            const float* __restrict__ alpha, const float* __restrict__ beta,
            int M, int N, int K, int kc)
{
  __shared__ alignas(16) char lds[131072];
  const int tid = threadIdx.x;
  const int l = tid & 63, w = tid >> 6;
  const int fl = l & 15, fh = l >> 4;
  const int wrm = w >> 2, wcn = w & 3;
  const int m0 = blockIdx.y * 256, n0 = blockIdx.x * 256;
  const int kBeg = blockIdx.z * kc;
  const int kEnd = (kBeg + kc < K) ? kBeg + kc : K;
  const int nt = (kEnd - kBeg) >> 6;

  f32x4 acc[8][4] = {};

  // staging: 1024 16B-loads per half-tile(128x64); thread does li = {tid, 512+tid}
  // li -> row = li>>3, slot = li&7; global col-slot = slot ^ (row&7)  ((row+64)&7==row&7)
  const int srow = tid >> 3;
  const int scol = ((tid & 7) ^ (srow & 7)) * 8;
  const ushort* Ag = A + (size_t)(m0 + srow) * K + kBeg + scol;
  const ushort* Bg = B + (size_t)(n0 + srow) * K + kBeg + scol;

  auto stA = [&](int buf, int half, int kt) {
    const ushort* g = Ag + (size_t)(half * 128) * K + kt * 64;
    char* d = lds + buf * 65536 + half * 16384 + tid * 16;
    gload16(g, d);
    gload16(g + (size_t)64 * K, d + 8192);
  };
  auto stB = [&](int buf, int half, int kt) {
    const ushort* g = Bg + (size_t)(half * 128) * K + kt * 64;
    char* d = lds + buf * 65536 + 32768 + half * 16384 + tid * 16;
    gload16(g, d);
    gload16(g + (size_t)64 * K, d + 8192);
  };

  // prologue: tile0 (A+B) + tile1 (B); wait tile0 landed (leave tile1's 4 loads in flight)
  stA(0, 0, 0); stA(0, 1, 0); stB(0, 0, 0); stB(0, 1, 0);
  if (nt > 1) {
    stB(1, 0, 1); stB(1, 1, 1);
    asm volatile("s_waitcnt vmcnt(4)" ::: "memory");
  } else {
    asm volatile("s_waitcnt vmcnt(0)" ::: "memory");
  }
  BAR();

  for (int s = 0; s < nt; ++s) {
    const int buf = s & 1;
    char* Ab = lds + buf * 65536;
    char* Bb = Ab + 32768;
    short8 a0[4][2], a1[4][2], b0[2][2], b1[2][2];

    // ---- phase 1: read a0(mf0-3) + b0(nf0-1); stage Ah0(s+1); MFMA Q00
#pragma unroll
    for (int mf = 0; mf < 4; ++mf)
#pragma unroll
      for (int ks = 0; ks < 2; ++ks) {
        int row = wrm * 128 + mf * 16 + fl;
        a0[mf][ks] = *(const short8*)(Ab + row * 128 + (((ks * 4 + fh) ^ (row & 7)) * 16));
      }
#pragma unroll
    for (int nf = 0; nf < 2; ++nf)
#pragma unroll
      for (int ks = 0; ks < 2; ++ks) {
        int row = wcn * 64 + nf * 16 + fl;
        b0[nf][ks] = *(const short8*)(Bb + row * 128 + (((ks * 4 + fh) ^ (row & 7)) * 16));
      }
    if (s + 1 < nt) stA(buf ^ 1, 0, s + 1);
    BAR(); WAITLG(); SCHED0(); PRIO1();
#pragma unroll
    for (int mf = 0; mf < 4; ++mf)
#pragma unroll
      for (int nf = 0; nf < 2; ++nf)
#pragma unroll
        for (int ks = 0; ks < 2; ++ks)
          acc[mf][nf] = __builtin_amdgcn_mfma_f32_16x16x32_bf16(a0[mf][ks], b0[nf][ks], acc[mf][nf], 0, 0, 0);
    PRIO0(); BAR();

    // ---- phase 2: read b1(nf2-3); stage Ah1(s+1); MFMA Q01 (a0 x b1)
#pragma unroll
    for (int nf = 0; nf < 2; ++nf)
#pragma unroll
      for (int ks = 0; ks < 2; ++ks) {
        int row = wcn * 64 + (nf + 2) * 16 + fl;
        b1[nf][ks] = *(const short8*)(Bb + row * 128 + (((ks * 4 + fh) ^ (row & 7)) * 16));
      }
    if (s + 1 < nt) stA(buf ^ 1, 1, s + 1);
    BAR(); WAITLG(); SCHED0(); PRIO1();
#pragma unroll
    for (int mf = 0; mf < 4; ++mf)
#pragma unroll
      for (int nf = 0; nf < 2; ++nf)
#pragma unroll
        for (int ks = 0; ks < 2; ++ks)
          acc[mf][nf + 2] = __builtin_amdgcn_mfma_f32_16x16x32_bf16(a0[mf][ks], b1[nf][ks], acc[mf][nf + 2], 0, 0, 0);
    PRIO0(); BAR();

    // ---- phase 3: read a1(mf4-7); stage Bh0(s+2) (B(s) consumed after ph2); MFMA Q10 (a1 x b0)
#pragma unroll
    for (int mf = 0; mf < 4; ++mf)
#pragma unroll
      for (int ks = 0; ks < 2; ++ks) {
        int row = wrm * 128 + (mf + 4) * 16 + fl;
        a1[mf][ks] = *(const short8*)(Ab + row * 128 + (((ks * 4 + fh) ^ (row & 7)) * 16));
      }
    if (s + 2 < nt) stB(buf, 0, s + 2);
    BAR(); WAITLG(); SCHED0(); PRIO1();
#pragma unroll
    for (int mf = 0; mf < 4; ++mf)
#pragma unroll
      for (int nf = 0; nf < 2; ++nf)
#pragma unroll
        for (int ks = 0; ks < 2; ++ks)
          acc[mf + 4][nf] = __builtin_amdgcn_mfma_f32_16x16x32_bf16(a1[mf][ks], b0[nf][ks], acc[mf + 4][nf], 0, 0, 0);
    PRIO0(); BAR();

    // ---- phase 4: stage Bh1(s+2); K-tile boundary vmcnt; MFMA Q11 (a1 x b1)
    if (s + 2 < nt) stB(buf, 1, s + 2);
    if (s + 1 < nt) {
      if (s + 2 < nt) asm volatile("s_waitcnt vmcnt(4)" ::: "memory");
      else            asm volatile("s_waitcnt vmcnt(0)" ::: "memory");
    }
    BAR(); PRIO1();
#pragma unroll
    for (int mf = 0; mf < 4; ++mf)
#pragma unroll
      for (int nf = 0; nf < 2; ++nf)
#pragma unroll
        for (int ks = 0; ks < 2; ++ks)
          acc[mf + 4][nf + 2] = __builtin_amdgcn_mfma_f32_16x16x32_bf16(a1[mf][ks], b1[nf][ks], acc[mf + 4][nf + 2], 0, 0, 0);
    PRIO0(); BAR();
  }

  const int orow0 = m0 + wrm * 128 + fh * 4;
  const int ocol0 = n0 + wcn * 64 + fl;
  float* Cpart = (EPI == 3) ? (Cf + (size_t)blockIdx.z * M * N) : Cf;
#pragma unroll
  for (int mf = 0; mf < 8; ++mf) {
#pragma unroll
    for (int nf = 0; nf < 4; ++nf) {
      const int c = ocol0 + nf * 16;
#pragma unroll
      for (int j = 0; j < 4; ++j) {
        const int r = orow0 + mf * 16 + j;
        const size_t o = (size_t)r * N + c;
        float v = acc[mf][nf][j];
        if constexpr (EPI == 1) {
          Cb[o] = (v - beta[c] > 0.f) ? f2b(alpha[c]) : (ushort)0;
        } else {
          Cpart[o] = v;
        }
      }
    }
  }
}

// ---------------- split-K reduce ----------------
// MODE 0: outf = sum ; MODE 1: outf = resid+sum, outb = hv(outf) ; MODE 2: outf = resid+sum
template<int NS, int MODE>
__global__ void reduce_kernel(const float* __restrict__ parts, int planeN4,
                              const float* __restrict__ resid,
                              float* __restrict__ outf, ushort* __restrict__ outb,
                              const float* __restrict__ alpha, const float* __restrict__ beta,
                              int n4, int cols)
{
  for (int i = blockIdx.x * blockDim.x + threadIdx.x; i < n4; i += gridDim.x * blockDim.x) {
    float4 s = ((const float4*)parts)[i];
#pragma unroll
    for (int z = 1; z < NS; ++z) {
      float4 p = ((const float4*)parts)[(size_t)z * planeN4 + i];
      s.x += p.x; s.y += p.y; s.z += p.z; s.w += p.w;
    }
    if constexpr (MODE >= 1) {
      float4 rr = ((const float4*)resid)[i];
      s.x += rr.x; s.y += rr.y; s.z += rr.z; s.w += rr.w;
    }
    ((float4*)outf)[i] = s;
    if constexpr (MODE == 1) {
      int c = (i * 4) & (cols - 1);
      ushort4 r;
      r.x = (s.x - beta[c] > 0.f) ? f2b(alpha[c]) : (ushort)0;
      r.y = (s.y - beta[c + 1] > 0.f) ? f2b(alpha[c + 1]) : (ushort)0;
      r.z = (s.z - beta[c + 2] > 0.f) ? f2b(alpha[c + 2]) : (ushort)0;
      r.w = (s.w - beta[c + 3] > 0.f) ? f2b(alpha[c + 3]) : (ushort)0;
      ((ushort4*)outb)[i] = r;
    }
  }
}

// ---------------- fused causal relu-attention ----------------
__global__ __launch_bounds__(256)
void attn_kernel(const ushort* __restrict__ qb, const ushort* __restrict__ kb,
                 const ushort* __restrict__ vt, ushort* __restrict__ hy,
                 const float* __restrict__ oalpha, const float* __restrict__ obeta)
{
  __shared__ alignas(16) ushort Qs[64 * 128];
  __shared__ alignas(16) ushort Ks[64 * 128];
  __shared__ alignas(16) ushort Vs[128 * 64];
  __shared__ alignas(16) ushort Ps[64 * 64];
  const int qi = blockIdx.x, h = blockIdx.y;
  const int g = h >> 2;
  const int q0 = qi * 64;
  const int tid = threadIdx.x;
  const int w = tid >> 6, l = tid & 63;
  const int fl = l & 15, fh = l >> 4;

#pragma unroll
  for (int i = 0; i < 4; ++i) {
    int row = w * 16 + i * 4 + (l >> 4);
    int c16 = (l & 15) ^ (row & 7);
    gload16(qb + (size_t)h * TT * DD + (size_t)(q0 + row) * DD + c16 * 8,
            (char*)Qs + (w << 12) + (i << 10) + (l << 4));
  }

  f32x4 oacc[8] = {};

  for (int s0 = 0; s0 <= q0; s0 += 64) {
#pragma unroll
    for (int i = 0; i < 4; ++i) {
      int row = w * 16 + i * 4 + (l >> 4);
      int c16 = (l & 15) ^ (row & 7);
      gload16(kb + (size_t)g * TT * DD + (size_t)(s0 + row) * DD + c16 * 8,
              (char*)Ks + (w << 12) + (i << 10) + (l << 4));
    }
#pragma unroll
    for (int i = 0; i < 4; ++i) {
      int d = w * 32 + i * 8 + (l >> 3);
      int c16 = (l & 7) ^ (d & 7);
      gload16(vt + (size_t)g * DD * TT + (size_t)d * TT + s0 + c16 * 8,
              (char*)Vs + (w << 12) + (i << 10) + (l << 4));
    }
    __syncthreads();

    f32x4 sacc[4] = {};
    const int qrow = w * 16 + fl;
#pragma unroll
    for (int ks = 0; ks < 4; ++ks) {
      int slotA = (ks * 4 + fh) ^ (qrow & 7);
      short8 a = *(const short8*)((char*)Qs + qrow * 256 + slotA * 16);
#pragma unroll
      for (int n = 0; n < 4; ++n) {
        int krow = n * 16 + fl;
        int slotB = (ks * 4 + fh) ^ (krow & 7);
        short8 b = *(const short8*)((char*)Ks + krow * 256 + slotB * 16);
        sacc[n] = __builtin_amdgcn_mfma_f32_16x16x32_bf16(a, b, sacc[n], 0, 0, 0);
      }
    }

#pragma unroll
    for (int n = 0; n < 4; ++n) {
      const int scol = s0 + n * 16 + fl;
#pragma unroll
      for (int j = 0; j < 4; ++j) {
        const int pr = w * 16 + fh * 4 + j;
        const int qr = q0 + pr;
        float v = sacc[n][j] * 0.0078125f;
        ushort pv = (scol <= qr && v > 0.f) ? f2b(v) : (ushort)0;
        int slot = ((n * 2) + (fl >> 3)) ^ (pr & 7);
        ((ushort*)((char*)Ps + pr * 128 + slot * 16))[fl & 7] = pv;
      }
    }

    const int prow = w * 16 + fl;
#pragma unroll
    for (int ks = 0; ks < 2; ++ks) {
      int slotA = (ks * 4 + fh) ^ (prow & 7);
      short8 pa = *(const short8*)((char*)Ps + prow * 128 + slotA * 16);
#pragma unroll
      for (int n = 0; n < 8; ++n) {
        int vrow = n * 16 + fl;
        int slotB = (ks * 4 + fh) ^ (vrow & 7);
        short8 vb = *(const short8*)((char*)Vs + vrow * 128 + slotB * 16);
        oacc[n] = __builtin_amdgcn_mfma_f32_16x16x32_bf16(pa, vb, oacc[n], 0, 0, 0);
      }
    }
    __syncthreads();
  }

#pragma unroll
  for (int n = 0; n < 8; ++n) {
    const int c = h * DD + n * 16 + fl;
    const float al = oalpha[c], be = obeta[c];
#pragma unroll
    for (int j = 0; j < 4; ++j) {
      const int tq = q0 + w * 16 + fh * 4 + j;
      float v = oacc[n][j];
      hy[(size_t)tq * CC + c] = (v - be > 0.f) ? f2b(al) : (ushort)0;
    }
  }
}

// ---------------- rope + hv on q/k, transpose+cast v ----------------
__global__ __launch_bounds__(256)
void rope_hv_kernel(const float* __restrict__ qkv, const float* __restrict__ cs,
                    const float* __restrict__ sn,
                    const float* __restrict__ qalpha, const float* __restrict__ qbeta,
                    const float* __restrict__ kalpha, const float* __restrict__ kbeta,
                    ushort* __restrict__ qb, ushort* __restrict__ kb,
                    ushort* __restrict__ vt)
{
  __shared__ ushort Vsh[64][129];
  const int t0 = blockIdx.x * 64, g = blockIdx.y;
  const int tid = threadIdx.x;
#pragma unroll
  for (int hh = 0; hh < 5; ++hh) {
    const float* alpha = (hh < 4) ? qalpha : kalpha;
    const float* beta = (hh < 4) ? qbeta : kbeta;
    const int hoff = (hh < 4) ? hh * 128 : 512;
    for (int it = 0; it < 16; ++it) {
      int idx = it * 256 + tid;
      int tr = idx >> 6, dd = idx & 63;
      size_t base = (size_t)(t0 + tr) * 3072 + g * 768 + hoff;
      float x1 = qkv[base + dd], x2 = qkv[base + 64 + dd];
      float c = cs[(size_t)(t0 + tr) * 64 + dd];
      float s = sn[(size_t)(t0 + tr) * 64 + dd];
      float o1 = x1 * c - x2 * s, o2 = x1 * s + x2 * c;
      ushort b1 = (o1 - beta[dd] > 0.f) ? f2b(alpha[dd]) : (ushort)0;
      ushort b2 = (o2 - beta[64 + dd] > 0.f) ? f2b(alpha[64 + dd]) : (ushort)0;
      if (hh < 4) {
        size_t o = ((size_t)(g * 4 + hh) * TT + t0 + tr) * DD;
        qb[o + dd] = b1;
        qb[o + 64 + dd] = b2;
      } else {
        size_t o = ((size_t)g * TT + t0 + tr) * DD;
        kb[o + dd] = b1;
        kb[o + 64 + dd] = b2;
      }
    }
  }
  for (int it = 0; it < 32; ++it) {
    int idx = it * 256 + tid;
    int tr = idx >> 7, d = idx & 127;
    Vsh[tr][d] = f2b(qkv[(size_t)(t0 + tr) * 3072 + g * 768 + 640 + d]);
  }
  __syncthreads();
  for (int it = 0; it < 32; ++it) {
    int idx = it * 256 + tid;
    int d = idx >> 6, tl = idx & 63;
    vt[((size_t)g * DD + d) * TT + t0 + tl] = Vsh[tl][d];
  }
}

// ---------------- elementwise ----------------
__global__ void hv_cast_kernel(const float* __restrict__ x, const float* __restrict__ alpha,
                               const float* __restrict__ beta, ushort* __restrict__ out,
                               int n4, int cols) {
  for (int i = blockIdx.x * blockDim.x + threadIdx.x; i < n4; i += gridDim.x * blockDim.x) {
    float4 v = ((const float4*)x)[i];
    int c = (i * 4) & (cols - 1);
    ushort4 r;
    r.x = (v.x - beta[c] > 0.f) ? f2b(alpha[c]) : (ushort)0;
    r.y = (v.y - beta[c + 1] > 0.f) ? f2b(alpha[c + 1]) : (ushort)0;
    r.z = (v.z - beta[c + 2] > 0.f) ? f2b(alpha[c + 2]) : (ushort)0;
    r.w = (v.w - beta[c + 3] > 0.f) ? f2b(alpha[c + 3]) : (ushort)0;
    ((ushort4*)out)[i] = r;
  }
}

__global__ void cast_kernel(const float* __restrict__ x, ushort* __restrict__ out, int n4) {
  for (int i = blockIdx.x * blockDim.x + threadIdx.x; i < n4; i += gridDim.x * blockDim.x) {
    float4 v = ((const float4*)x)[i];
    ushort4 r;
    r.x = f2b(v.x); r.y = f2b(v.y); r.z = f2b(v.z); r.w = f2b(v.w);
    ((ushort4*)out)[i] = r;
  }
}

__global__ void norm_cast_kernel(const float* __restrict__ W, const float* __restrict__ mu,
                                 const float* __restrict__ inv, ushort* __restrict__ out,
                                 int n4, int cols) {
  for (int i = blockIdx.x * blockDim.x + threadIdx.x; i < n4; i += gridDim.x * blockDim.x) {
    float4 v = ((const float4*)W)[i];
    int c = (i * 4) & (cols - 1);
    ushort4 r;
    r.x = f2b((v.x - mu[c]) * inv[c]);
    r.y = f2b((v.y - mu[c + 1]) * inv[c + 1]);
    r.z = f2b((v.z - mu[c + 2]) * inv[c + 2]);
    r.w = f2b((v.w - mu[c + 3]) * inv[c + 3]);
    ((ushort4*)out)[i] = r;
  }
}

// ---------------- column stats ----------------
__global__ void stats1_kernel(const float* __restrict__ W, float* __restrict__ ps,
                              float* __restrict__ ps2, int cols) {
  int j = blockIdx.x * 256 + threadIdx.x;
  int chunk = blockIdx.y;
  const float* p = W + (size_t)chunk * 256 * cols + j;
  float s = 0.f, s2 = 0.f;
  for (int i = 0; i < 256; ++i) { float v = p[(size_t)i * cols]; s += v; s2 += v * v; }
  ps[chunk * cols + j] = s;
  ps2[chunk * cols + j] = s2;
}

__global__ void stats2_kernel(const float* __restrict__ ps, const float* __restrict__ ps2,
                              float* __restrict__ mu, float* __restrict__ inv,
                              const float* __restrict__ scale, int cols) {
  int j = blockIdx.x * 256 + threadIdx.x;
  float s = 0.f, s2 = 0.f;
  for (int c = 0; c < 8; ++c) { s += ps[c * cols + j]; s2 += ps2[c * cols + j]; }
  float m = s * (1.f / 2048.f);
  float var = s2 - s * m;
  float nn = sqrtf(fmaxf(var, 0.f));
  nn = fmaxf(nn, 1e-12f);
  mu[j] = m;
  inv[j] = scale[0] / nn;
}

extern "C" void kernel_launch(void* const* d_in, const int* in_sizes, int n_in,
                              void* d_out, int out_size, void* d_ws, size_t ws_size,
                              hipStream_t stream) {
  const float* x          = (const float*)d_in[0];
  const float* cosT       = (const float*)d_in[1];
  const float* sinT       = (const float*)d_in[2];
  const float* attn_w     = (const float*)d_in[3];
  const float* proj_w     = (const float*)d_in[4];
  const float* proj_scale = (const float*)d_in[5];
  const float* fc_w       = (const float*)d_in[6];
  const float* mlp_proj_w = (const float*)d_in[7];
  const float* mlp_scale  = (const float*)d_in[8];
  const float* in_alpha   = (const float*)d_in[9];
  const float* in_beta    = (const float*)d_in[10];
  const float* q_alpha    = (const float*)d_in[11];
  const float* q_beta     = (const float*)d_in[12];
  const float* k_alpha    = (const float*)d_in[13];
  const float* k_beta     = (const float*)d_in[14];
  const float* out_alpha  = (const float*)d_in[15];
  const float* out_beta   = (const float*)d_in[16];
  const float* act1_alpha = (const float*)d_in[17];
  const float* act1_beta  = (const float*)d_in[18];
  const float* act2_alpha = (const float*)d_in[19];
  const float* act2_beta  = (const float*)d_in[20];

  char* cur = (char*)d_ws;
  auto alloc = [&](size_t b) { void* p = cur; cur += (b + 255) & ~(size_t)255; return p; };

  // --- early-dead cluster (dead after attn): 58.7MB contiguous ---
  ushort* attn_wb = (ushort*)alloc((size_t)3072 * 2048 * 2);   // 12.58MB, dead after qkv GEMM
  ushort* h_in    = (ushort*)alloc((size_t)2048 * 2048 * 2);   //  8.39MB, dead after qkv GEMM
  float*  qkv     = (float*)alloc((size_t)2048 * 3072 * 4);    // 25.17MB, dead after rope
  ushort* qbuf    = (ushort*)alloc((size_t)HQ * TT * DD * 2);  //  8.39MB, dead after attn
  ushort* kbuf    = (ushort*)alloc((size_t)GG * TT * DD * 2);  //  2.10MB, dead after attn
  ushort* vtbuf   = (ushort*)alloc((size_t)GG * DD * TT * 2);  //  2.10MB, dead after attn
  // --- mid-dead ---
  ushort* projn   = (ushort*)alloc((size_t)2048 * 2048 * 2);   //  8.39MB, dead after proj GEMM
  ushort* fc_wb   = (ushort*)alloc((size_t)8192 * 2048 * 2);   // 33.55MB, dead after fc GEMM
  // --- live-late ---
  ushort* mlpn    = (ushort*)alloc((size_t)2048 * 8192 * 2);
  ushort* h_y     = (ushort*)alloc((size_t)2048 * 2048 * 2);
  float*  x2      = (float*)alloc((size_t)2048 * 2048 * 4);
  ushort* h2      = (ushort*)alloc((size_t)2048 * 2048 * 2);
  ushort* h3      = (ushort*)alloc((size_t)2048 * 8192 * 2);
  float* pp_s  = (float*)alloc(8 * 2048 * 4);
  float* pp_s2 = (float*)alloc(8 * 2048 * 4);
  float* mp_s  = (float*)alloc(8 * 8192 * 4);
  float* mp_s2 = (float*)alloc(8 * 8192 * 4);
  float* p_mu  = (float*)alloc(2048 * 4);
  float* p_inv = (float*)alloc(2048 * 4);
  float* m_mu  = (float*)alloc(8192 * 4);
  float* m_inv = (float*)alloc(8192 * 4);

  // split-K part planes alias dead contiguous regions:
  float* qkv_parts  = (float*)x2;       // 2 x 25.17 = 50.3MB over [x2,h2,h3] = 58.7MB (written later)
  float* proj_parts = (float*)attn_wb;  // 3 x 16.78 = 50.3MB over early-dead cluster = 58.7MB
  float* mlp_parts  = (float*)attn_wb;  // 4 x 16.78 = 67.1MB over [cluster,projn,fc_wb] = 100.7MB

  // weight prep
  stats1_kernel<<<dim3(8, 8), 256, 0, stream>>>(proj_w, pp_s, pp_s2, 2048);
  stats1_kernel<<<dim3(32, 8), 256, 0, stream>>>(mlp_proj_w, mp_s, mp_s2, 8192);
  stats2_kernel<<<8, 256, 0, stream>>>(pp_s, pp_s2, p_mu, p_inv, proj_scale, 2048);
  stats2_kernel<<<32, 256, 0, stream>>>(mp_s, mp_s2, m_mu, m_inv, mlp_scale, 8192);
  norm_cast_kernel<<<2048, 256, 0, stream>>>(proj_w, p_mu, p_inv, projn, 2048 * 2048 / 4, 2048);
  norm_cast_kernel<<<2048, 256, 0, stream>>>(mlp_proj_w, m_mu, m_inv, mlpn, 2048 * 8192 / 4, 8192);
  cast_kernel<<<2048, 256, 0, stream>>>(attn_w, attn_wb, 3072 * 2048 / 4);
  cast_kernel<<<2048, 256, 0, stream>>>(fc_w, fc_wb, 8192 * 2048 / 4);

  // h = hv(x)
  hv_cast_kernel<<<2048, 256, 0, stream>>>(x, in_alpha, in_beta, h_in, 2048 * 2048 / 4, 2048);

  // qkv = h @ attn_w^T   (split-K x2, 192 blocks)
  gemm8p<3><<<dim3(3072 / 256, 2048 / 256, 2), 512, 0, stream>>>(
      h_in, attn_wb, qkv_parts, nullptr, nullptr, nullptr, 2048, 3072, 2048, 1024);
  reduce_kernel<2, 0><<<2048, 256, 0, stream>>>(
      qkv_parts, 2048 * 3072 / 4, nullptr, qkv, nullptr, nullptr, nullptr, 2048 * 3072 / 4, 1);

  // rope + hv -> q,k ; transpose v
  rope_hv_kernel<<<dim3(TT / 64, GG), 256, 0, stream>>>(
      qkv, cosT, sinT, q_alpha, q_beta, k_alpha, k_beta, qbuf, kbuf, vtbuf);

  // fused causal relu attention, hv epilogue -> h_y
  attn_kernel<<<dim3(TT / 64, HQ), 256, 0, stream>>>(qbuf, kbuf, vtbuf, h_y, out_alpha, out_beta);

  // x2 = x + h_y @ projn^T (split-K x3, kc=704 -> 11/11/10 K-tiles), fused h2 = hv(x2)
  gemm8p<3><<<dim3(2048 / 256, 2048 / 256, 3), 512, 0, stream>>>(
      h_y, projn, proj_parts, nullptr, nullptr, nullptr, 2048, 2048, 2048, 704);
  reduce_kernel<3, 1><<<2048, 256, 0, stream>>>(
      proj_parts, 2048 * 2048 / 4, x, x2, h2, act1_alpha, act1_beta, 2048 * 2048 / 4, 2048);

  // h3 = hv(h2 @ fc_w^T)   (256 blocks, 1/CU, no split)
  gemm8p<1><<<dim3(8192 / 256, 2048 / 256, 1), 512, 0, stream>>>(
      h2, fc_wb, nullptr, h3, act2_alpha, act2_beta, 2048, 8192, 2048, 2048);

  // out = x2 + h3 @ mlpn^T (split-K x4, kc=2048)
  gemm8p<3><<<dim3(2048 / 256, 2048 / 256, 4), 512, 0, stream>>>(
      h3, mlpn, mlp_parts, nullptr, nullptr, nullptr, 2048, 2048, 8192, 2048);
  reduce_kernel<4, 2><<<2048, 256, 0, stream>>>(
      mlp_parts, 2048 * 2048 / 4, x2, (float*)d_out, nullptr, nullptr, nullptr, 2048 * 2048 / 4, 1);
}

// Round 4
// 461.885 us; speedup vs baseline: 1.4495x; 1.0288x over previous
//
#include <hip/hip_runtime.h>

typedef __attribute__((ext_vector_type(8))) short short8;
typedef __attribute__((ext_vector_type(4))) float f32x4;

constexpr int TT = 2048, CC = 2048, HQ = 16, GG = 4, DD = 128, IC = 8192;

__device__ __forceinline__ ushort f2b(float f) {
  union { float f; unsigned u; } v; v.f = f;
  unsigned r = v.u + 0x7fffu + ((v.u >> 16) & 1u);
  return (ushort)(r >> 16);
}

__device__ __forceinline__ void gload16(const void* g, void* l) {
  __builtin_amdgcn_global_load_lds(
      (const __attribute__((address_space(1))) void*)g,
      (__attribute__((address_space(3))) void*)l, 16, 0, 0);
}

#define BARM()   asm volatile("s_barrier" ::: "memory")
#define PRIO1()  __builtin_amdgcn_s_setprio(1)
#define PRIO0()  __builtin_amdgcn_s_setprio(0)

// ============ 256x256 GEMM: C[M,N] = A[M,K](bf16) @ B[N,K](bf16)^T ============
// EPI 1: Cb = hv(acc, alpha, beta) bf16 ; EPI 3: f32 partial plane per blockIdx.z
// 8 waves (2M x 4N), per-wave 128x64 output, BK=64, 128KB LDS double-buffered.
// v2 schedule: stages 2 K-tiles ahead into just-freed regions of the CURRENT
// buffer (B(t+2)h0@ph2, B(t+2)h1@ph3, A(t+2)h0+h1@ph4); boundary vmcnt(8) once
// per tile; fragment ds_reads pipelined one phase ahead. All stage-vs-read
// pairs barrier-separated. 5 barriers/K-tile.
template<int EPI>
__global__ __launch_bounds__(512, 2)
void gemm8p(const ushort* __restrict__ A, const ushort* __restrict__ B,
            float* __restrict__ Cf, ushort* __restrict__ Cb,
            const float* __restrict__ alpha, const float* __restrict__ beta,
            int M, int N, int K, int kc)
{
  __shared__ alignas(16) char lds[131072];
  const int tid = threadIdx.x;
  const int l = tid & 63, w = tid >> 6;
  const int fl = l & 15, fh = l >> 4;
  const int wrm = w >> 2, wcn = w & 3;
  const int m0 = blockIdx.y * 256, n0 = blockIdx.x * 256;
  const int kBeg = blockIdx.z * kc;
  const int kEnd = (kBeg + kc < K) ? kBeg + kc : K;
  const int nt = (kEnd - kBeg) >> 6;

  f32x4 acc[8][4] = {};

  // staging: pre-swizzled global source, linear LDS dest (both-sides rule)
  const int srow = tid >> 3;
  const int scol = ((tid & 7) ^ (srow & 7)) * 8;
  const ushort* Ag = A + (size_t)(m0 + srow) * K + kBeg + scol;
  const ushort* Bg = B + (size_t)(n0 + srow) * K + kBeg + scol;

  auto stA = [&](int buf, int half, int kt) {
    const ushort* g = Ag + (size_t)(half * 128) * K + kt * 64;
    char* d = lds + buf * 65536 + half * 16384 + tid * 16;
    gload16(g, d);
    gload16(g + (size_t)64 * K, d + 8192);
  };
  auto stB = [&](int buf, int half, int kt) {
    const ushort* g = Bg + (size_t)(half * 128) * K + kt * 64;
    char* d = lds + buf * 65536 + 32768 + half * 16384 + tid * 16;
    gload16(g, d);
    gload16(g + (size_t)64 * K, d + 8192);
  };

  short8 A0[4][2], A1[4][2], B0[2][2], B1[2][2];

  auto readA = [&](short8 (&dst)[4][2], int buf, int mofs) {
#pragma unroll
    for (int mf = 0; mf < 4; ++mf)
#pragma unroll
      for (int ks = 0; ks < 2; ++ks) {
        int row = wrm * 128 + (mofs + mf) * 16 + fl;
        dst[mf][ks] = *(const short8*)(lds + buf * 65536 + row * 128 +
                                       (((ks * 4 + fh) ^ (row & 7)) * 16));
      }
  };
  auto readB = [&](short8 (&dst)[2][2], int buf, int nofs) {
#pragma unroll
    for (int nf = 0; nf < 2; ++nf)
#pragma unroll
      for (int ks = 0; ks < 2; ++ks) {
        int row = wcn * 64 + (nofs + nf) * 16 + fl;
        dst[nf][ks] = *(const short8*)(lds + buf * 65536 + 32768 + row * 128 +
                                       (((ks * 4 + fh) ^ (row & 7)) * 16));
      }
  };
  auto mmQ = [&](short8 (&a)[4][2], short8 (&b)[2][2], int mo, int no) {
    PRIO1();
#pragma unroll
    for (int mf = 0; mf < 4; ++mf)
#pragma unroll
      for (int nf = 0; nf < 2; ++nf)
#pragma unroll
        for (int ks = 0; ks < 2; ++ks)
          acc[mo + mf][no + nf] = __builtin_amdgcn_mfma_f32_16x16x32_bf16(
              a[mf][ks], b[nf][ks], acc[mo + mf][no + nf], 0, 0, 0);
    PRIO0();
  };

  // prologue: tile0 + tile1 staged; wait tile0 (tile1's 8 loads stay in flight)
  stA(0, 0, 0); stA(0, 1, 0); stB(0, 0, 0); stB(0, 1, 0);
  if (nt > 1) {
    stA(1, 0, 1); stA(1, 1, 1); stB(1, 0, 1); stB(1, 1, 1);
    asm volatile("s_waitcnt vmcnt(8)" ::: "memory");
  } else {
    asm volatile("s_waitcnt vmcnt(0)" ::: "memory");
  }
  BARM();
  readA(A0, 0, 0);
  readB(B0, 0, 0);

  for (int t = 0; t < nt; ++t) {
    const int buf = t & 1;
    const bool st2 = (t + 2 < nt);
    // ph1: read B1(t); MFMA Q00 (A0 x B0)
    readB(B1, buf, 2);
    mmQ(A0, B0, 0, 0);
    BARM();
    // ph2: read A1(t); stage B(t+2)h0 (B h0 reads were last phase, barrier-sep); MFMA Q01 (A0 x B1)
    readA(A1, buf, 4);
    if (st2) stB(buf, 0, t + 2);
    mmQ(A0, B1, 0, 2);
    BARM();
    // ph3: stage B(t+2)h1; MFMA Q10 (A1 x B0)
    if (st2) stB(buf, 1, t + 2);
    mmQ(A1, B0, 4, 0);
    BARM();
    // ph4: stage A(t+2)h0,h1; boundary vmcnt; BAR; read next tile A0,B0; MFMA Q11 (A1 x B1)
    if (st2) {
      stA(buf, 0, t + 2); stA(buf, 1, t + 2);
      asm volatile("s_waitcnt vmcnt(8)" ::: "memory");   // 8 = this tile's issues; drains t+1
    } else {
      asm volatile("s_waitcnt vmcnt(0)" ::: "memory");
    }
    BARM();
    if (t + 1 < nt) {
      readA(A0, buf ^ 1, 0);
      readB(B0, buf ^ 1, 0);
    }
    mmQ(A1, B1, 4, 2);
    BARM();
  }

  const int orow0 = m0 + wrm * 128 + fh * 4;
  const int ocol0 = n0 + wcn * 64 + fl;
  float* Cpart = (EPI == 3) ? (Cf + (size_t)blockIdx.z * M * N) : Cf;
#pragma unroll
  for (int mf = 0; mf < 8; ++mf) {
#pragma unroll
    for (int nf = 0; nf < 4; ++nf) {
      const int c = ocol0 + nf * 16;
#pragma unroll
      for (int j = 0; j < 4; ++j) {
        const int r = orow0 + mf * 16 + j;
        const size_t o = (size_t)r * N + c;
        float v = acc[mf][nf][j];
        if constexpr (EPI == 1) {
          Cb[o] = (v - beta[c] > 0.f) ? f2b(alpha[c]) : (ushort)0;
        } else {
          Cpart[o] = v;
        }
      }
    }
  }
}

// ---------------- split-K reduce ----------------
// MODE 1: outf = resid+sum, outb = hv(outf) ; MODE 2: outf = resid+sum
template<int NS, int MODE>
__global__ void reduce_kernel(const float* __restrict__ parts, int planeN4,
                              const float* __restrict__ resid,
                              float* __restrict__ outf, ushort* __restrict__ outb,
                              const float* __restrict__ alpha, const float* __restrict__ beta,
                              int n4, int cols)
{
  for (int i = blockIdx.x * blockDim.x + threadIdx.x; i < n4; i += gridDim.x * blockDim.x) {
    float4 s = ((const float4*)parts)[i];
#pragma unroll
    for (int z = 1; z < NS; ++z) {
      float4 p = ((const float4*)parts)[(size_t)z * planeN4 + i];
      s.x += p.x; s.y += p.y; s.z += p.z; s.w += p.w;
    }
    if constexpr (MODE >= 1) {
      float4 rr = ((const float4*)resid)[i];
      s.x += rr.x; s.y += rr.y; s.z += rr.z; s.w += rr.w;
    }
    ((float4*)outf)[i] = s;
    if constexpr (MODE == 1) {
      int c = (i * 4) & (cols - 1);
      ushort4 r;
      r.x = (s.x - beta[c] > 0.f) ? f2b(alpha[c]) : (ushort)0;
      r.y = (s.y - beta[c + 1] > 0.f) ? f2b(alpha[c + 1]) : (ushort)0;
      r.z = (s.z - beta[c + 2] > 0.f) ? f2b(alpha[c + 2]) : (ushort)0;
      r.w = (s.w - beta[c + 3] > 0.f) ? f2b(alpha[c + 3]) : (ushort)0;
      ((ushort4*)outb)[i] = r;
    }
  }
}

// ---------------- fused causal relu-attention ----------------
__global__ __launch_bounds__(256)
void attn_kernel(const ushort* __restrict__ qb, const ushort* __restrict__ kb,
                 const ushort* __restrict__ vt, ushort* __restrict__ hy,
                 const float* __restrict__ oalpha, const float* __restrict__ obeta)
{
  __shared__ alignas(16) ushort Qs[64 * 128];
  __shared__ alignas(16) ushort Ks[64 * 128];
  __shared__ alignas(16) ushort Vs[128 * 64];
  __shared__ alignas(16) ushort Ps[64 * 64];
  const int qi = gridDim.x - 1 - blockIdx.x;   // heavy q-tiles dispatch first
  const int h = blockIdx.y;
  const int g = h >> 2;
  const int q0 = qi * 64;
  const int tid = threadIdx.x;
  const int w = tid >> 6, l = tid & 63;
  const int fl = l & 15, fh = l >> 4;

#pragma unroll
  for (int i = 0; i < 4; ++i) {
    int row = w * 16 + i * 4 + (l >> 4);
    int c16 = (l & 15) ^ (row & 7);
    gload16(qb + (size_t)h * TT * DD + (size_t)(q0 + row) * DD + c16 * 8,
            (char*)Qs + (w << 12) + (i << 10) + (l << 4));
  }

  f32x4 oacc[8] = {};

  for (int s0 = 0; s0 <= q0; s0 += 64) {
#pragma unroll
    for (int i = 0; i < 4; ++i) {
      int row = w * 16 + i * 4 + (l >> 4);
      int c16 = (l & 15) ^ (row & 7);
      gload16(kb + (size_t)g * TT * DD + (size_t)(s0 + row) * DD + c16 * 8,
              (char*)Ks + (w << 12) + (i << 10) + (l << 4));
    }
#pragma unroll
    for (int i = 0; i < 4; ++i) {
      int d = w * 32 + i * 8 + (l >> 3);
      int c16 = (l & 7) ^ (d & 7);
      gload16(vt + (size_t)g * DD * TT + (size_t)d * TT + s0 + c16 * 8,
              (char*)Vs + (w << 12) + (i << 10) + (l << 4));
    }
    __syncthreads();

    f32x4 sacc[4] = {};
    const int qrow = w * 16 + fl;
#pragma unroll
    for (int ks = 0; ks < 4; ++ks) {
      int slotA = (ks * 4 + fh) ^ (qrow & 7);
      short8 a = *(const short8*)((char*)Qs + qrow * 256 + slotA * 16);
#pragma unroll
      for (int n = 0; n < 4; ++n) {
        int krow = n * 16 + fl;
        int slotB = (ks * 4 + fh) ^ (krow & 7);
        short8 b = *(const short8*)((char*)Ks + krow * 256 + slotB * 16);
        sacc[n] = __builtin_amdgcn_mfma_f32_16x16x32_bf16(a, b, sacc[n], 0, 0, 0);
      }
    }

#pragma unroll
    for (int n = 0; n < 4; ++n) {
      const int scol = s0 + n * 16 + fl;
#pragma unroll
      for (int j = 0; j < 4; ++j) {
        const int pr = w * 16 + fh * 4 + j;
        const int qr = q0 + pr;
        float v = sacc[n][j] * 0.0078125f;
        ushort pv = (scol <= qr && v > 0.f) ? f2b(v) : (ushort)0;
        int slot = ((n * 2) + (fl >> 3)) ^ (pr & 7);
        ((ushort*)((char*)Ps + pr * 128 + slot * 16))[fl & 7] = pv;
      }
    }

    const int prow = w * 16 + fl;
#pragma unroll
    for (int ks = 0; ks < 2; ++ks) {
      int slotA = (ks * 4 + fh) ^ (prow & 7);
      short8 pa = *(const short8*)((char*)Ps + prow * 128 + slotA * 16);
#pragma unroll
      for (int n = 0; n < 8; ++n) {
        int vrow = n * 16 + fl;
        int slotB = (ks * 4 + fh) ^ (vrow & 7);
        short8 vb = *(const short8*)((char*)Vs + vrow * 128 + slotB * 16);
        oacc[n] = __builtin_amdgcn_mfma_f32_16x16x32_bf16(pa, vb, oacc[n], 0, 0, 0);
      }
    }
    __syncthreads();
  }

#pragma unroll
  for (int n = 0; n < 8; ++n) {
    const int c = h * DD + n * 16 + fl;
    const float al = oalpha[c], be = obeta[c];
#pragma unroll
    for (int j = 0; j < 4; ++j) {
      const int tq = q0 + w * 16 + fh * 4 + j;
      float v = oacc[n][j];
      hy[(size_t)tq * CC + c] = (v - be > 0.f) ? f2b(al) : (ushort)0;
    }
  }
}

// ---------- rope + hv on q/k, transpose+cast v ; fused split-K-2 sum ----------
__global__ __launch_bounds__(256)
void rope_hv_kernel(const float* __restrict__ qp0, const float* __restrict__ qp1,
                    const float* __restrict__ cs, const float* __restrict__ sn,
                    const float* __restrict__ qalpha, const float* __restrict__ qbeta,
                    const float* __restrict__ kalpha, const float* __restrict__ kbeta,
                    ushort* __restrict__ qb, ushort* __restrict__ kb,
                    ushort* __restrict__ vt)
{
  __shared__ ushort Vsh[64][129];
  const int t0 = blockIdx.x * 64, g = blockIdx.y;
  const int tid = threadIdx.x;
#pragma unroll
  for (int hh = 0; hh < 5; ++hh) {
    const float* alpha = (hh < 4) ? qalpha : kalpha;
    const float* beta = (hh < 4) ? qbeta : kbeta;
    const int hoff = (hh < 4) ? hh * 128 : 512;
    for (int it = 0; it < 16; ++it) {
      int idx = it * 256 + tid;
      int tr = idx >> 6, dd = idx & 63;
      size_t base = (size_t)(t0 + tr) * 3072 + g * 768 + hoff;
      float x1 = qp0[base + dd] + qp1[base + dd];
      float x2 = qp0[base + 64 + dd] + qp1[base + 64 + dd];
      float c = cs[(size_t)(t0 + tr) * 64 + dd];
      float s = sn[(size_t)(t0 + tr) * 64 + dd];
      float o1 = x1 * c - x2 * s, o2 = x1 * s + x2 * c;
      ushort b1 = (o1 - beta[dd] > 0.f) ? f2b(alpha[dd]) : (ushort)0;
      ushort b2 = (o2 - beta[64 + dd] > 0.f) ? f2b(alpha[64 + dd]) : (ushort)0;
      if (hh < 4) {
        size_t o = ((size_t)(g * 4 + hh) * TT + t0 + tr) * DD;
        qb[o + dd] = b1;
        qb[o + 64 + dd] = b2;
      } else {
        size_t o = ((size_t)g * TT + t0 + tr) * DD;
        kb[o + dd] = b1;
        kb[o + 64 + dd] = b2;
      }
    }
  }
  for (int it = 0; it < 32; ++it) {
    int idx = it * 256 + tid;
    int tr = idx >> 7, d = idx & 127;
    size_t src = (size_t)(t0 + tr) * 3072 + g * 768 + 640 + d;
    Vsh[tr][d] = f2b(qp0[src] + qp1[src]);
  }
  __syncthreads();
  for (int it = 0; it < 32; ++it) {
    int idx = it * 256 + tid;
    int d = idx >> 6, tl = idx & 63;
    vt[((size_t)g * DD + d) * TT + t0 + tl] = Vsh[tl][d];
  }
}

// ---------------- elementwise ----------------
__global__ void hv_cast_kernel(const float* __restrict__ x, const float* __restrict__ alpha,
                               const float* __restrict__ beta, ushort* __restrict__ out,
                               int n4, int cols) {
  for (int i = blockIdx.x * blockDim.x + threadIdx.x; i < n4; i += gridDim.x * blockDim.x) {
    float4 v = ((const float4*)x)[i];
    int c = (i * 4) & (cols - 1);
    ushort4 r;
    r.x = (v.x - beta[c] > 0.f) ? f2b(alpha[c]) : (ushort)0;
    r.y = (v.y - beta[c + 1] > 0.f) ? f2b(alpha[c + 1]) : (ushort)0;
    r.z = (v.z - beta[c + 2] > 0.f) ? f2b(alpha[c + 2]) : (ushort)0;
    r.w = (v.w - beta[c + 3] > 0.f) ? f2b(alpha[c + 3]) : (ushort)0;
    ((ushort4*)out)[i] = r;
  }
}

__global__ void cast_kernel(const float* __restrict__ x, ushort* __restrict__ out, int n4) {
  for (int i = blockIdx.x * blockDim.x + threadIdx.x; i < n4; i += gridDim.x * blockDim.x) {
    float4 v = ((const float4*)x)[i];
    ushort4 r;
    r.x = f2b(v.x); r.y = f2b(v.y); r.z = f2b(v.z); r.w = f2b(v.w);
    ((ushort4*)out)[i] = r;
  }
}

__global__ void norm_cast_kernel(const float* __restrict__ W, const float* __restrict__ mu,
                                 const float* __restrict__ inv, ushort* __restrict__ out,
                                 int n4, int cols) {
  for (int i = blockIdx.x * blockDim.x + threadIdx.x; i < n4; i += gridDim.x * blockDim.x) {
    float4 v = ((const float4*)W)[i];
    int c = (i * 4) & (cols - 1);
    ushort4 r;
    r.x = f2b((v.x - mu[c]) * inv[c]);
    r.y = f2b((v.y - mu[c + 1]) * inv[c + 1]);
    r.z = f2b((v.z - mu[c + 2]) * inv[c + 2]);
    r.w = f2b((v.w - mu[c + 3]) * inv[c + 3]);
    ((ushort4*)out)[i] = r;
  }
}

// ---------------- column stats ----------------
__global__ void stats1_kernel(const float* __restrict__ W, float* __restrict__ ps,
                              float* __restrict__ ps2, int cols) {
  int j = blockIdx.x * 256 + threadIdx.x;
  int chunk = blockIdx.y;
  const float* p = W + (size_t)chunk * 256 * cols + j;
  float s = 0.f, s2 = 0.f;
  for (int i = 0; i < 256; ++i) { float v = p[(size_t)i * cols]; s += v; s2 += v * v; }
  ps[chunk * cols + j] = s;
  ps2[chunk * cols + j] = s2;
}

__global__ void stats2_kernel(const float* __restrict__ ps, const float* __restrict__ ps2,
                              float* __restrict__ mu, float* __restrict__ inv,
                              const float* __restrict__ scale, int cols) {
  int j = blockIdx.x * 256 + threadIdx.x;
  float s = 0.f, s2 = 0.f;
  for (int c = 0; c < 8; ++c) { s += ps[c * cols + j]; s2 += ps2[c * cols + j]; }
  float m = s * (1.f / 2048.f);
  float var = s2 - s * m;
  float nn = sqrtf(fmaxf(var, 0.f));
  nn = fmaxf(nn, 1e-12f);
  mu[j] = m;
  inv[j] = scale[0] / nn;
}

extern "C" void kernel_launch(void* const* d_in, const int* in_sizes, int n_in,
                              void* d_out, int out_size, void* d_ws, size_t ws_size,
                              hipStream_t stream) {
  const float* x          = (const float*)d_in[0];
  const float* cosT       = (const float*)d_in[1];
  const float* sinT       = (const float*)d_in[2];
  const float* attn_w     = (const float*)d_in[3];
  const float* proj_w     = (const float*)d_in[4];
  const float* proj_scale = (const float*)d_in[5];
  const float* fc_w       = (const float*)d_in[6];
  const float* mlp_proj_w = (const float*)d_in[7];
  const float* mlp_scale  = (const float*)d_in[8];
  const float* in_alpha   = (const float*)d_in[9];
  const float* in_beta    = (const float*)d_in[10];
  const float* q_alpha    = (const float*)d_in[11];
  const float* q_beta     = (const float*)d_in[12];
  const float* k_alpha    = (const float*)d_in[13];
  const float* k_beta     = (const float*)d_in[14];
  const float* out_alpha  = (const float*)d_in[15];
  const float* out_beta   = (const float*)d_in[16];
  const float* act1_alpha = (const float*)d_in[17];
  const float* act1_beta  = (const float*)d_in[18];
  const float* act2_alpha = (const float*)d_in[19];
  const float* act2_beta  = (const float*)d_in[20];

  char* cur = (char*)d_ws;
  auto alloc = [&](size_t b) { void* p = cur; cur += (b + 255) & ~(size_t)255; return p; };

  // --- early-dead cluster (dead after attn): contiguous ---
  ushort* attn_wb = (ushort*)alloc((size_t)3072 * 2048 * 2);
  ushort* h_in    = (ushort*)alloc((size_t)2048 * 2048 * 2);
  float*  qkv     = (float*)alloc((size_t)2048 * 3072 * 4);   // (unused scratch, kept for layout)
  ushort* qbuf    = (ushort*)alloc((size_t)HQ * TT * DD * 2);
  ushort* kbuf    = (ushort*)alloc((size_t)GG * TT * DD * 2);
  ushort* vtbuf   = (ushort*)alloc((size_t)GG * DD * TT * 2);
  // --- mid-dead ---
  ushort* projn   = (ushort*)alloc((size_t)2048 * 2048 * 2);
  ushort* fc_wb   = (ushort*)alloc((size_t)8192 * 2048 * 2);
  // --- live-late ---
  ushort* mlpn    = (ushort*)alloc((size_t)2048 * 8192 * 2);
  ushort* h_y     = (ushort*)alloc((size_t)2048 * 2048 * 2);
  float*  x2      = (float*)alloc((size_t)2048 * 2048 * 4);
  ushort* h2      = (ushort*)alloc((size_t)2048 * 2048 * 2);
  ushort* h3      = (ushort*)alloc((size_t)2048 * 8192 * 2);
  float* pp_s  = (float*)alloc(8 * 2048 * 4);
  float* pp_s2 = (float*)alloc(8 * 2048 * 4);
  float* mp_s  = (float*)alloc(8 * 8192 * 4);
  float* mp_s2 = (float*)alloc(8 * 8192 * 4);
  float* p_mu  = (float*)alloc(2048 * 4);
  float* p_inv = (float*)alloc(2048 * 4);
  float* m_mu  = (float*)alloc(8192 * 4);
  float* m_inv = (float*)alloc(8192 * 4);

  // split-K part planes alias dead contiguous regions:
  float* qkv_parts  = (float*)x2;       // 2 x 25.17MB over [x2,h2,h3]=58.7MB (written later)
  float* proj_parts = (float*)attn_wb;  // 3 x 16.78MB over early-dead cluster
  float* mlp_parts  = (float*)attn_wb;  // 4 x 16.78MB over [cluster,projn,fc_wb]

  // weight prep
  stats1_kernel<<<dim3(8, 8), 256, 0, stream>>>(proj_w, pp_s, pp_s2, 2048);
  stats1_kernel<<<dim3(32, 8), 256, 0, stream>>>(mlp_proj_w, mp_s, mp_s2, 8192);
  stats2_kernel<<<8, 256, 0, stream>>>(pp_s, pp_s2, p_mu, p_inv, proj_scale, 2048);
  stats2_kernel<<<32, 256, 0, stream>>>(mp_s, mp_s2, m_mu, m_inv, mlp_scale, 8192);
  norm_cast_kernel<<<2048, 256, 0, stream>>>(proj_w, p_mu, p_inv, projn, 2048 * 2048 / 4, 2048);
  norm_cast_kernel<<<2048, 256, 0, stream>>>(mlp_proj_w, m_mu, m_inv, mlpn, 2048 * 8192 / 4, 8192);
  cast_kernel<<<2048, 256, 0, stream>>>(attn_w, attn_wb, 3072 * 2048 / 4);
  cast_kernel<<<2048, 256, 0, stream>>>(fc_w, fc_wb, 8192 * 2048 / 4);

  // h = hv(x)
  hv_cast_kernel<<<2048, 256, 0, stream>>>(x, in_alpha, in_beta, h_in, 2048 * 2048 / 4, 2048);

  // qkv = h @ attn_w^T   (split-K x2; sum fused into rope)
  gemm8p<3><<<dim3(3072 / 256, 2048 / 256, 2), 512, 0, stream>>>(
      h_in, attn_wb, qkv_parts, nullptr, nullptr, nullptr, 2048, 3072, 2048, 1024);

  // rope + hv -> q,k ; transpose v  (reads & sums the two qkv part planes)
  rope_hv_kernel<<<dim3(TT / 64, GG), 256, 0, stream>>>(
      qkv_parts, qkv_parts + (size_t)2048 * 3072, cosT, sinT,
      q_alpha, q_beta, k_alpha, k_beta, qbuf, kbuf, vtbuf);

  // fused causal relu attention, hv epilogue -> h_y
  attn_kernel<<<dim3(TT / 64, HQ), 256, 0, stream>>>(qbuf, kbuf, vtbuf, h_y, out_alpha, out_beta);

  // x2 = x + h_y @ projn^T (split-K x3, kc=704 -> 11/11/10 K-tiles), fused h2 = hv(x2)
  gemm8p<3><<<dim3(2048 / 256, 2048 / 256, 3), 512, 0, stream>>>(
      h_y, projn, proj_parts, nullptr, nullptr, nullptr, 2048, 2048, 2048, 704);
  reduce_kernel<3, 1><<<2048, 256, 0, stream>>>(
      proj_parts, 2048 * 2048 / 4, x, x2, h2, act1_alpha, act1_beta, 2048 * 2048 / 4, 2048);

  // h3 = hv(h2 @ fc_w^T)   (256 blocks, 1/CU, no split)
  gemm8p<1><<<dim3(8192 / 256, 2048 / 256, 1), 512, 0, stream>>>(
      h2, fc_wb, nullptr, h3, act2_alpha, act2_beta, 2048, 8192, 2048, 2048);

  // out = x2 + h3 @ mlpn^T (split-K x4, kc=2048)
  gemm8p<3><<<dim3(2048 / 256, 2048 / 256, 4), 512, 0, stream>>>(
      h3, mlpn, mlp_parts, nullptr, nullptr, nullptr, 2048, 2048, 8192, 2048);
  reduce_kernel<4, 2><<<2048, 256, 0, stream>>>(
      mlp_parts, 2048 * 2048 / 4, x2, (float*)d_out, nullptr, nullptr, nullptr, 2048 * 2048 / 4, 1);
}